// Round 3
// baseline (412.446 us; speedup 1.0000x reference)
//
#include <hip/hip_runtime.h>
#include <cstdint>

#define S_LEN 2048
#define D_MODEL 1024
#define NH 16
#define HDIM 64
#define BATCH 4

typedef __attribute__((ext_vector_type(8))) __bf16 bfrag;   // 8 bf16 = 4 VGPR
typedef __attribute__((ext_vector_type(4))) float ffrag;    // 4 f32 acc

__device__ __forceinline__ unsigned short f2bf(float f) {
    union { float f; uint32_t u; } v; v.f = f;
    uint32_t u = v.u;
    u += 0x7fff + ((u >> 16) & 1);   // round-to-nearest-even
    return (unsigned short)(u >> 16);
}

__device__ __forceinline__ bfrag ld_frag(const unsigned short* p) {
    union { uint4 u; bfrag b; } x;
    x.u = *(const uint4*)p;
    return x.b;
}

__device__ __forceinline__ float fast_exp2(float x) {
#if __has_builtin(__builtin_amdgcn_exp2f)
    return __builtin_amdgcn_exp2f(x);
#else
    return __expf(x * 0.6931471805599453f);
#endif
}

// pack two f32 -> packed bf16x2 (round-half-up), 3 VALU inst
__device__ __forceinline__ uint32_t pack_bf16(float a, float b) {
    union { float f; uint32_t u; } x, y; x.f = a; y.f = b;
    return __builtin_amdgcn_perm(y.u + 0x8000u, x.u + 0x8000u, 0x07060302u);
}

__device__ __forceinline__ void g2l16(const unsigned short* g, unsigned short* l) {
    __builtin_amdgcn_global_load_lds(
        (const __attribute__((address_space(1))) void*)g,
        (__attribute__((address_space(3))) void*)l, 16, 0, 0);
}

// -------- fused prep: cast x (fp32->bf16) + cast/transpose weights ----------
__global__ __launch_bounds__(256) void prep_kernel(const float* __restrict__ x,
                                                   const float* __restrict__ w0,
                                                   const float* __restrict__ w1,
                                                   const float* __restrict__ w2,
                                                   const float* __restrict__ w3,
                                                   unsigned short* __restrict__ xb,
                                                   unsigned short* __restrict__ wt) {
    __shared__ float tile[32][33];
    int bid = blockIdx.x;
    int t = threadIdx.x;
    if (bid < 4096) {
        int i = bid * 256 + t;
        const float4* p = (const float4*)x + (size_t)i * 2;
        float4 a = p[0], b = p[1];
        union { unsigned short u[8]; uint4 v; } o;
        o.u[0]=f2bf(a.x); o.u[1]=f2bf(a.y); o.u[2]=f2bf(a.z); o.u[3]=f2bf(a.w);
        o.u[4]=f2bf(b.x); o.u[5]=f2bf(b.y); o.u[6]=f2bf(b.z); o.u[7]=f2bf(b.w);
        ((uint4*)xb)[i] = o.v;
    } else {
        int r = bid - 4096;
        int mat = r >> 10;
        int rem = r & 1023;
        const float* w = (mat == 0) ? w0 : (mat == 1) ? w1 : (mat == 2) ? w2 : w3;
        int n0 = (rem & 31) * 32, k0 = (rem >> 5) * 32;
        int tx = t & 31, ty = t >> 5;   // 32 x 8
        for (int i = 0; i < 32; i += 8)
            tile[ty + i][tx] = w[(size_t)(k0 + ty + i) * D_MODEL + n0 + tx];
        __syncthreads();
        unsigned short* o = wt + (size_t)mat * D_MODEL * D_MODEL;
        for (int i = 0; i < 32; i += 8)
            o[(size_t)(n0 + ty + i) * D_MODEL + (k0 + tx)] = f2bf(tile[tx][ty + i]);
    }
}

// ------------- V transpose: Vb[bh][s][d] -> Vtb[bh][d][s] (bf16) -------------
__global__ __launch_bounds__(256) void transpose_v_kernel(const unsigned short* __restrict__ Vb,
                                                          unsigned short* __restrict__ Vtb) {
    __shared__ unsigned short tile[64][72];
    int st = blockIdx.x;   // s-tile of 64
    int bh = blockIdx.y;
    int t = threadIdx.x;
    int sl = t >> 2, dc = (t & 3) * 16;
    const unsigned short* src = Vb + ((size_t)bh * S_LEN + st * 64 + sl) * HDIM + dc;
    *(uint4*)&tile[sl][dc]     = *(const uint4*)(src);
    *(uint4*)&tile[sl][dc + 8] = *(const uint4*)(src + 8);
    __syncthreads();
    int d = t >> 2, sc = (t & 3) * 16;
    union { unsigned short u[16]; uint4 v[2]; } o;
#pragma unroll
    for (int i = 0; i < 16; i++) o.u[i] = tile[sc + i][d];
    unsigned short* dst = Vtb + ((size_t)bh * HDIM + d) * S_LEN + st * 64 + sc;
    *(uint4*)(dst)     = o.v[0];
    *(uint4*)(dst + 8) = o.v[1];
}

// ---------------- GEMM: C[M][N] = A[M][K=1024] * Bt[N][K]^T ----------------
// R15: 256x256 tile, 8 waves (2M x 4N, wave tile 128x64 = m201 geometry),
// BK=32, 512 threads. Sync schedule is BYTE-IDENTICAL in form to the proven
// R13/R14 loop (passed R2): triple-buffered, 2-deep prefetch, per iter
//   s_waitcnt vmcnt(4); s_barrier   (fused asm) + sched_barrier(0),
// prefetch kt+2, ds_read frags, MFMA cluster; peeled last tile at vmcnt(0).
// Why: R2 counters showed the 128^2/2-barrier structure at its ceiling
// (MfmaUtil 22, VALU 24, LDS ~30%, all pipes idle -> structural). 256^2
// halves LDS-bytes/MFMA (512->384B) and doubles MFMA-per-barrier per wave
// (16->32). LDS 96KB (3 x 32KB) -> 1 block/CU, 2 waves/SIMD.
// XOR chunk swizzle identical to R2 (2-way conflicts only, free).
// Per-thread staging: 2 chunks per matrix (c0=t, c1=512+t) -> 4 g2l16/tile
// -> vmcnt(4) counts exactly one tile, same as R13. Watch VGPR (acc 8x4=128;
// spill would show as WRITE_SIZE blowup per R4 history).
#define GBUF2 8192   // elems per matrix per buffer: 256 rows * 32
#define NKT  (D_MODEL / 32)   // 32 k-tiles

__global__ __launch_bounds__(512, 2) void gemm_kernel(
    const unsigned short* __restrict__ A,
    const unsigned short* __restrict__ Bt,
    int mode,                                // 0 = QKV scatter, 1 = out + bias
    unsigned short* __restrict__ Qb,
    unsigned short* __restrict__ Kb,
    unsigned short* __restrict__ Vb,
    float* __restrict__ Out,
    const float* __restrict__ bias) {
    __shared__ unsigned short As[3 * GBUF2];
    __shared__ unsigned short Bs[3 * GBUF2];
    int t = threadIdx.x;

    // T1: XCD-aware remap (bijective: nwg = 384 or 128, both % 8 == 0)
    int gx   = (int)gridDim.x;
    int nwg  = gx * (int)gridDim.y;
    int flat = (int)(blockIdx.y * gridDim.x + blockIdx.x);
    int cpx  = nwg >> 3;
    int wid  = (flat & 7) * cpx + (flat >> 3);
    int m0 = (wid / gx) * 256;
    int n0 = (wid % gx) * 256;

    int wave = t >> 6, lane = t & 63;
    int quad = lane >> 4, lrow = lane & 15;
    int wr = (wave & 1) * 128;    // M offset of wave tile
    int wc = (wave >> 1) * 64;    // N offset of wave tile

    ffrag acc[8][4];
    const ffrag fz = {0.f, 0.f, 0.f, 0.f};
#pragma unroll
    for (int i = 0; i < 8; i++)
#pragma unroll
        for (int j = 0; j < 4; j++) acc[i][j] = fz;

    // staging: 1024 chunks of 8 elems per matrix per tile; thread t covers
    // chunk c0 = t and c1 = 512+t (4 chunk-groups per 32-elem row)
    int c0 = t, c1 = 512 + t;
    int r0 = c0 >> 2, g0 = (c0 & 3) ^ ((r0 >> 1) & 3);
    int r1 = c1 >> 2, g1 = (c1 & 3) ^ ((r1 >> 1) & 3);
    const unsigned short* A0 = A + (size_t)(m0 + r0) * D_MODEL + g0 * 8;
    const unsigned short* A1 = A + (size_t)(m0 + r1) * D_MODEL + g1 * 8;
    const unsigned short* B0 = Bt + (size_t)(n0 + r0) * D_MODEL + g0 * 8;
    const unsigned short* B1 = Bt + (size_t)(n0 + r1) * D_MODEL + g1 * 8;
    unsigned short* lA0 = &As[(wave * 64) * 8];
    unsigned short* lA1 = &As[(512 + wave * 64) * 8];
    unsigned short* lB0 = &Bs[(wave * 64) * 8];
    unsigned short* lB1 = &Bs[(512 + wave * 64) * 8];

    // prologue: tile 0 -> buf 0, tile 1 -> buf 1 (4 g2l per tile, FIFO order)
    g2l16(A0, lA0);
    g2l16(A1, lA1);
    g2l16(B0, lB0);
    g2l16(B1, lB1);
    g2l16(A0 + 32, lA0 + GBUF2);
    g2l16(A1 + 32, lA1 + GBUF2);
    g2l16(B0 + 32, lB0 + GBUF2);
    g2l16(B1 + 32, lB1 + GBUF2);

    int bufA = 0, bufB = GBUF2, bufC = 2 * GBUF2;   // kt, kt+1, kt+2 buffers

    for (int kt = 0; kt < NKT - 1; ++kt) {
        // wait for tile kt's 4 loads only; tile kt+1's ride across the barrier
        asm volatile("s_waitcnt vmcnt(4)\n\ts_barrier" ::: "memory");
        __builtin_amdgcn_sched_barrier(0);
        if (kt + 2 < NKT) {
            int ko = (kt + 2) * 32;
            g2l16(A0 + ko, lA0 + bufC);
            g2l16(A1 + ko, lA1 + bufC);
            g2l16(B0 + ko, lB0 + bufC);
            g2l16(B1 + ko, lB1 + bufC);
        }
        bfrag bf[4];
#pragma unroll
        for (int ni = 0; ni < 4; ni++) {
            int row = wc + ni * 16 + lrow;
            bf[ni] = ld_frag(&Bs[bufA + row * 32 + ((quad ^ ((row >> 1) & 3)) * 8)]);
        }
#pragma unroll
        for (int mi = 0; mi < 8; mi++) {
            int row = wr + mi * 16 + lrow;
            bfrag a = ld_frag(&As[bufA + row * 32 + ((quad ^ ((row >> 1) & 3)) * 8)]);
#pragma unroll
            for (int ni = 0; ni < 4; ni++)
                acc[mi][ni] = __builtin_amdgcn_mfma_f32_16x16x32_bf16(a, bf[ni], acc[mi][ni], 0, 0, 0);
        }
        int tmp = bufA; bufA = bufB; bufB = bufC; bufC = tmp;
    }
    // peeled last tile: only its own 4 loads outstanding -> full drain
    asm volatile("s_waitcnt vmcnt(0)\n\ts_barrier" ::: "memory");
    __builtin_amdgcn_sched_barrier(0);
    {
        bfrag bf[4];
#pragma unroll
        for (int ni = 0; ni < 4; ni++) {
            int row = wc + ni * 16 + lrow;
            bf[ni] = ld_frag(&Bs[bufA + row * 32 + ((quad ^ ((row >> 1) & 3)) * 8)]);
        }
#pragma unroll
        for (int mi = 0; mi < 8; mi++) {
            int row = wr + mi * 16 + lrow;
            bfrag a = ld_frag(&As[bufA + row * 32 + ((quad ^ ((row >> 1) & 3)) * 8)]);
#pragma unroll
            for (int ni = 0; ni < 4; ni++)
                acc[mi][ni] = __builtin_amdgcn_mfma_f32_16x16x32_bf16(a, bf[ni], acc[mi][ni], 0, 0, 0);
        }
    }

    // epilogue — C element: row = m0+wr+mi*16+quad*4+r, col = n0+wc+ni*16+lrow
    for (int mi = 0; mi < 8; mi++) {
        int row = m0 + wr + mi * 16 + quad * 4;
        for (int ni = 0; ni < 4; ni++) {
            int col = n0 + wc + ni * 16 + lrow;
            for (int r = 0; r < 4; r++) {
                float v = acc[mi][ni][r];
                int m = row + r;
                if (mode == 0) {
                    int matid = col >> 10;
                    int nn = col & 1023;
                    int h = nn >> 6, d = nn & 63;
                    int b = m >> 11, s = m & 2047;
                    size_t bh = (size_t)(b * NH + h);
                    if (matid == 0)      Qb[(bh * S_LEN + s) * HDIM + d] = f2bf(v);
                    else if (matid == 1) Kb[(bh * S_LEN + s) * HDIM + d] = f2bf(v);
                    else                 Vb[(bh * S_LEN + s) * HDIM + d] = f2bf(v);
                } else {
                    Out[(size_t)m * D_MODEL + col] = v + bias[col];
                }
            }
        }
    }
}

// ---------------- flash attention v10 (transposed-S, dbuf, split-q), causal ----------------
// (unchanged from R2 pass: 64-row q chunks, grid (16,64), XCD remap, dbuf
// K/V staging, fixed-shift softmax, ones-MFMA l, LDS-transposed epilogue)
#define SCALE2 0.18033688f  // 1/sqrt(64) * log2(e)
#define CSHIFT 4.0f
#define KVBUF 4096          // elems per K (or V) buffer: 64*64

__global__ __launch_bounds__(256, 4) void attn_kernel(
    const unsigned short* __restrict__ Qb,
    const unsigned short* __restrict__ Kb,
    const unsigned short* __restrict__ Vtb,
    unsigned short* __restrict__ ctxb) {
    __shared__ unsigned short Ks[2 * KVBUF];      // [buf][key][d]  swizzled
    __shared__ unsigned short Vs[2 * KVBUF];      // [buf][d][key]  swizzled
    __shared__ unsigned short Ps[4 * 16 * 64];    // per wave: [q(16)][key(64)] swizzled
    int flat = (int)(blockIdx.y * gridDim.x + blockIdx.x);   // 1024 blocks
    int wid  = (flat & 7) * 128 + (flat >> 3);
    int bx = wid & 15;    // 0..15
    int bh = wid >> 4;    // 0..63
    int t = threadIdx.x;
    int wave = t >> 6, lane = t & 63;
    int quad = lane >> 4, lrow = lane & 15;
    int swz = lrow & 7;
    int ca = (quad ^ swz) * 8;        // physical elem offset of logical chunk quad
    int cb = ca ^ 32;                 // logical chunk quad+4

    union { uint4 u; bfrag b; } one_u;
    one_u.u.x = 0x3F803F80u; one_u.u.y = 0x3F803F80u;
    one_u.u.z = 0x3F803F80u; one_u.u.w = 0x3F803F80u;
    bfrag onef = one_u.b;             // all-ones A-frag for l row-sum MFMA

    const unsigned short* Qg = Qb + (size_t)bh * S_LEN * HDIM;
    const unsigned short* Kg = Kb + (size_t)bh * S_LEN * HDIM;
    const unsigned short* Vg = Vtb + (size_t)bh * HDIM * S_LEN;
    int b = bh >> 4, h = bh & 15;

    // staging chunk assignment (512 chunks per 64x64 tile, 2 per thread)
    int c0 = t, c1 = 256 + t;
    int kr0 = c0 >> 3, kp0 = (c0 & 7) ^ (kr0 & 7);
    int kr1 = c1 >> 3, kp1 = (c1 & 7) ^ (kr1 & 7);
    const unsigned short* pK0 = Kg + (size_t)kr0 * HDIM + kp0 * 8;
    const unsigned short* pK1 = Kg + (size_t)kr1 * HDIM + kp1 * 8;
    const unsigned short* pV0 = Vg + (size_t)kr0 * S_LEN + kp0 * 8;
    const unsigned short* pV1 = Vg + (size_t)kr1 * S_LEN + kp1 * 8;
    unsigned short* lK0 = &Ks[(wave * 64) * 8];
    unsigned short* lK1 = &Ks[(256 + wave * 64) * 8];
    unsigned short* lV0 = &Vs[(wave * 64) * 8];
    unsigned short* lV1 = &Vs[(256 + wave * 64) * 8];
    unsigned short* Pw = &Ps[wave * 16 * 64];

    for (int ph = 0; ph < 2; ph++) {
        int qc = ph == 0 ? (31 - bx) : bx;   // 64-row q chunk index
        int qw = qc * 64 + wave * 16;
        int nk = qc + 1;

        bfrag qf[2];
#pragma unroll
        for (int c = 0; c < 2; c++)
            qf[c] = ld_frag(Qg + (size_t)(qw + lrow) * HDIM + c * 32 + quad * 8);

        ffrag acc[4];
        ffrag acc_l;
        const ffrag fz = {0.f, 0.f, 0.f, 0.f};
#pragma unroll
        for (int d = 0; d < 4; d++) acc[d] = fz;
        acc_l = fz;

        // phase prologue: buffers free (prev phase/kernel-start), preload tile 0
        __syncthreads();
        g2l16(pK0, lK0);
        g2l16(pK1, lK1);
        g2l16(pV0, lV0);
        g2l16(pV1, lV1);

        for (int kt = 0; kt < nk; kt++) {
            int kbase = kt * 64;
            int buf = (kt & 1) * KVBUF;
            __syncthreads();
            if (kt + 1 < nk) {
                int nb = ((kt + 1) & 1) * KVBUF;
                size_t krow_off = (size_t)(kbase + 64) * HDIM;
                g2l16(pK0 + krow_off, lK0 + nb);
                g2l16(pK1 + krow_off, lK1 + nb);
                g2l16(pV0 + kbase + 64, lV0 + nb);
                g2l16(pV1 + kbase + 64, lV1 + nb);
            }

            // ---- S^T = K Q^T ----
            ffrag sf[4];
#pragma unroll
            for (int ki = 0; ki < 4; ki++) {
                int krow = buf + (ki * 16 + lrow) * 64;
                bfrag ka = ld_frag(&Ks[krow + ca]);
                bfrag kb = ld_frag(&Ks[krow + cb]);
                ffrag s = fz;
                s = __builtin_amdgcn_mfma_f32_16x16x32_bf16(ka, qf[0], s, 0, 0, 0);
                s = __builtin_amdgcn_mfma_f32_16x16x32_bf16(kb, qf[1], s, 0, 0, 0);
                sf[ki] = s;
            }

            // ---- fixed-shift softmax (mask only on the diagonal tile) ----
            int qg = qw + lrow;                  // this lane's q
            bool need_mask = (kt == nk - 1);     // block-uniform
            float sv[16];
#pragma unroll
            for (int ki = 0; ki < 4; ki++)
#pragma unroll
                for (int r = 0; r < 4; r++) {
                    float v = sf[ki][r];
                    if (need_mask) {
                        int key = kbase + ki * 16 + quad * 4 + r;
                        v = (key <= qg) ? v : -3.0e38f;
                    }
                    sv[ki * 4 + r] = fast_exp2(__builtin_fmaf(v, SCALE2, -CSHIFT));
                }
            // P store [q][key] swizzled: logical chunk 2ki+(quad>>1)
            int prow = lrow * 64;
#pragma unroll
            for (int ki = 0; ki < 4; ki++) {
                uint2 w2;
                w2.x = pack_bf16(sv[ki * 4 + 0], sv[ki * 4 + 1]);
                w2.y = pack_bf16(sv[ki * 4 + 2], sv[ki * 4 + 3]);
                int pc = ((ki * 2 + (quad >> 1)) ^ swz) * 8 + (quad & 1) * 4;
                *(uint2*)&Pw[prow + pc] = w2;
            }

            // ---- O^T += V^T P^T ----  (Pw wave-private, DS in-order: no barrier)
            bfrag pf0 = ld_frag(&Pw[prow + ca]);
            bfrag pf1 = ld_frag(&Pw[prow + cb]);
            acc_l = __builtin_amdgcn_mfma_f32_16x16x32_bf16(onef, pf0, acc_l, 0, 0, 0);
            acc_l = __builtin_amdgcn_mfma_f32_16x16x32_bf16(onef, pf1, acc_l, 0, 0, 0);
#pragma unroll
            for (int di = 0; di < 4; di++) {
                int vrow = buf + (di * 16 + lrow) * 64;
                bfrag va = ld_frag(&Vs[vrow + ca]);
                bfrag vb = ld_frag(&Vs[vrow + cb]);
                acc[di] = __builtin_amdgcn_mfma_f32_16x16x32_bf16(va, pf0, acc[di], 0, 0, 0);
                acc[di] = __builtin_amdgcn_mfma_f32_16x16x32_bf16(vb, pf1, acc[di], 0, 0, 0);
            }
        }

        // epilogue: transpose O^T -> O via wave-private LDS, coalesced 16B stores.
        float rl = __builtin_amdgcn_rcpf(acc_l[0]);  // all rows equal; lane lrow=q
#pragma unroll
        for (int di = 0; di < 4; di++) {
            uint2 w2;
            w2.x = pack_bf16(acc[di][0] * rl, acc[di][1] * rl);
            w2.y = pack_bf16(acc[di][2] * rl, acc[di][3] * rl);
            *(uint2*)&Pw[lrow * 64 + di * 16 + quad * 4] = w2;
        }
        int ql = lane >> 3, cc = lane & 7;
#pragma unroll
        for (int p = 0; p < 2; p++) {
            uint4 vv = *(uint4*)&Pw[(p * 8 + ql) * 64 + cc * 8];
            int q = qw + p * 8 + ql;
            *(uint4*)(ctxb + ((size_t)b * S_LEN + q) * D_MODEL + h * HDIM + cc * 8) = vv;
        }
    }
}

extern "C" void kernel_launch(void* const* d_in, const int* in_sizes, int n_in,
                              void* d_out, int out_size, void* d_ws, size_t ws_size,
                              hipStream_t stream) {
    const float* x   = (const float*)d_in[0];
    const float* W_q = (const float*)d_in[1];
    const float* W_k = (const float*)d_in[2];
    const float* W_v = (const float*)d_in[3];
    const float* W_o = (const float*)d_in[4];
    const float* b_o = (const float*)d_in[5];
    float* out = (float*)d_out;

    // workspace carve (elems, ushort).  Vb (row-layout V) aliases ctxb:
    // Vb is dead after transpose_v, before attn writes ctxb.
    unsigned short* xb   = (unsigned short*)d_ws;                    // 8192*1024
    unsigned short* Wt   = xb + (size_t)8192 * 1024;                 // 4*1024*1024
    unsigned short* Qb   = Wt + (size_t)4 * 1024 * 1024;             // 64*2048*64
    unsigned short* Kb   = Qb + (size_t)64 * 2048 * 64;
    unsigned short* Vtb  = Kb + (size_t)64 * 2048 * 64;
    unsigned short* ctxb = Vtb + (size_t)64 * 2048 * 64;             // 8192*1024
    unsigned short* Vb   = ctxb;
    unsigned short* Wto  = Wt + (size_t)3 * 1024 * 1024;

    // fused cast + weight transpose (one launch)
    prep_kernel<<<8192, 256, 0, stream>>>(x, W_q, W_k, W_v, W_o, xb, Wt);
    // QKV: M=8192, N=3072 (V written row-layout [s][d]); 256^2 tiles, 512 thr
    gemm_kernel<<<dim3(12, 32), 512, 0, stream>>>(xb, Wt, 0, Qb, Kb, Vb, nullptr, nullptr);
    // V transpose [s][d] -> [d][s]
    transpose_v_kernel<<<dim3(32, 64), 256, 0, stream>>>(Vb, Vtb);
    // attention (split-q: block bx does 64-row chunks 31-bx then bx; 33 tiles each)
    attn_kernel<<<dim3(16, 64), 256, 0, stream>>>(Qb, Kb, Vtb, ctxb);
    // out proj: M=8192, N=1024, + bias; 256^2 tiles, 512 thr
    gemm_kernel<<<dim3(4, 32), 512, 0, stream>>>(ctxb, Wto, 1, nullptr, nullptr, nullptr, out, b_o);
}

// Round 4
// 306.860 us; speedup vs baseline: 1.3441x; 1.3441x over previous
//
#include <hip/hip_runtime.h>
#include <cstdint>

#define S_LEN 2048
#define D_MODEL 1024
#define NH 16
#define HDIM 64
#define BATCH 4

typedef __attribute__((ext_vector_type(8))) __bf16 bfrag;   // 8 bf16 = 4 VGPR
typedef __attribute__((ext_vector_type(4))) float ffrag;    // 4 f32 acc

__device__ __forceinline__ unsigned short f2bf(float f) {
    union { float f; uint32_t u; } v; v.f = f;
    uint32_t u = v.u;
    u += 0x7fff + ((u >> 16) & 1);   // round-to-nearest-even
    return (unsigned short)(u >> 16);
}

__device__ __forceinline__ bfrag ld_frag(const unsigned short* p) {
    union { uint4 u; bfrag b; } x;
    x.u = *(const uint4*)p;
    return x.b;
}

__device__ __forceinline__ float fast_exp2(float x) {
#if __has_builtin(__builtin_amdgcn_exp2f)
    return __builtin_amdgcn_exp2f(x);
#else
    return __expf(x * 0.6931471805599453f);
#endif
}

// pack two f32 -> packed bf16x2 (round-half-up), 3 VALU inst
__device__ __forceinline__ uint32_t pack_bf16(float a, float b) {
    union { float f; uint32_t u; } x, y; x.f = a; y.f = b;
    return __builtin_amdgcn_perm(y.u + 0x8000u, x.u + 0x8000u, 0x07060302u);
}

__device__ __forceinline__ void g2l16(const unsigned short* g, unsigned short* l) {
    __builtin_amdgcn_global_load_lds(
        (const __attribute__((address_space(1))) void*)g,
        (__attribute__((address_space(3))) void*)l, 16, 0, 0);
}

// -------- fused prep: cast x (fp32->bf16) + cast/transpose weights ----------
__global__ __launch_bounds__(256) void prep_kernel(const float* __restrict__ x,
                                                   const float* __restrict__ w0,
                                                   const float* __restrict__ w1,
                                                   const float* __restrict__ w2,
                                                   const float* __restrict__ w3,
                                                   unsigned short* __restrict__ xb,
                                                   unsigned short* __restrict__ wt) {
    __shared__ float tile[32][33];
    int bid = blockIdx.x;
    int t = threadIdx.x;
    if (bid < 4096) {
        int i = bid * 256 + t;
        const float4* p = (const float4*)x + (size_t)i * 2;
        float4 a = p[0], b = p[1];
        union { unsigned short u[8]; uint4 v; } o;
        o.u[0]=f2bf(a.x); o.u[1]=f2bf(a.y); o.u[2]=f2bf(a.z); o.u[3]=f2bf(a.w);
        o.u[4]=f2bf(b.x); o.u[5]=f2bf(b.y); o.u[6]=f2bf(b.z); o.u[7]=f2bf(b.w);
        ((uint4*)xb)[i] = o.v;
    } else {
        int r = bid - 4096;
        int mat = r >> 10;
        int rem = r & 1023;
        const float* w = (mat == 0) ? w0 : (mat == 1) ? w1 : (mat == 2) ? w2 : w3;
        int n0 = (rem & 31) * 32, k0 = (rem >> 5) * 32;
        int tx = t & 31, ty = t >> 5;   // 32 x 8
        for (int i = 0; i < 32; i += 8)
            tile[ty + i][tx] = w[(size_t)(k0 + ty + i) * D_MODEL + n0 + tx];
        __syncthreads();
        unsigned short* o = wt + (size_t)mat * D_MODEL * D_MODEL;
        for (int i = 0; i < 32; i += 8)
            o[(size_t)(n0 + ty + i) * D_MODEL + (k0 + tx)] = f2bf(tile[tx][ty + i]);
    }
}

// ------------- V transpose: Vb[bh][s][d] -> Vtb[bh][d][s] (bf16) -------------
__global__ __launch_bounds__(256) void transpose_v_kernel(const unsigned short* __restrict__ Vb,
                                                          unsigned short* __restrict__ Vtb) {
    __shared__ unsigned short tile[64][72];
    int st = blockIdx.x;   // s-tile of 64
    int bh = blockIdx.y;
    int t = threadIdx.x;
    int sl = t >> 2, dc = (t & 3) * 16;
    const unsigned short* src = Vb + ((size_t)bh * S_LEN + st * 64 + sl) * HDIM + dc;
    *(uint4*)&tile[sl][dc]     = *(const uint4*)(src);
    *(uint4*)&tile[sl][dc + 8] = *(const uint4*)(src + 8);
    __syncthreads();
    int d = t >> 2, sc = (t & 3) * 16;
    union { unsigned short u[16]; uint4 v[2]; } o;
#pragma unroll
    for (int i = 0; i < 16; i++) o.u[i] = tile[sc + i][d];
    unsigned short* dst = Vtb + ((size_t)bh * HDIM + d) * S_LEN + st * 64 + sc;
    *(uint4*)(dst)     = o.v[0];
    *(uint4*)(dst + 8) = o.v[1];
}

// ---------------- GEMM: C[M][N] = A[M][K=1024] * Bt[N][K]^T ----------------
// R15: 256x256 tile, 8 waves (2M x 4N, wave tile 128x64 = m201 geometry),
// BK=32, 512 threads. Triple-buffered, 2-deep prefetch, per iter
//   s_waitcnt vmcnt(4); s_barrier   (fused asm) + sched_barrier(0),
// prefetch kt+2, ds_read frags, MFMA cluster; peeled last tile at vmcnt(0).
// R16 FIX: R3 regression (171us, WRITE 275MB, VGPR_Count 92) was rule-#20
// scratch spill: the 8x4x4 EPILOGUE loops were not unrolled -> runtime
// acc[mi][ni][r] indexing -> whole acc array materialized in scratch
// (~200MB round-trip/dispatch). Fix: #pragma unroll on ALL epilogue loops
// so every acc access is compile-time-indexed. Main loop untouched.
// XOR chunk swizzle identical to R2 (2-way conflicts only, free).
#define GBUF2 8192   // elems per matrix per buffer: 256 rows * 32
#define NKT  (D_MODEL / 32)   // 32 k-tiles

__global__ __launch_bounds__(512, 2) void gemm_kernel(
    const unsigned short* __restrict__ A,
    const unsigned short* __restrict__ Bt,
    int mode,                                // 0 = QKV scatter, 1 = out + bias
    unsigned short* __restrict__ Qb,
    unsigned short* __restrict__ Kb,
    unsigned short* __restrict__ Vb,
    float* __restrict__ Out,
    const float* __restrict__ bias) {
    __shared__ unsigned short As[3 * GBUF2];
    __shared__ unsigned short Bs[3 * GBUF2];
    int t = threadIdx.x;

    // T1: XCD-aware remap (bijective: nwg = 384 or 128, both % 8 == 0)
    int gx   = (int)gridDim.x;
    int nwg  = gx * (int)gridDim.y;
    int flat = (int)(blockIdx.y * gridDim.x + blockIdx.x);
    int cpx  = nwg >> 3;
    int wid  = (flat & 7) * cpx + (flat >> 3);
    int m0 = (wid / gx) * 256;
    int n0 = (wid % gx) * 256;

    int wave = t >> 6, lane = t & 63;
    int quad = lane >> 4, lrow = lane & 15;
    int wr = (wave & 1) * 128;    // M offset of wave tile
    int wc = (wave >> 1) * 64;    // N offset of wave tile

    ffrag acc[8][4];
    const ffrag fz = {0.f, 0.f, 0.f, 0.f};
#pragma unroll
    for (int i = 0; i < 8; i++)
#pragma unroll
        for (int j = 0; j < 4; j++) acc[i][j] = fz;

    // staging: 1024 chunks of 8 elems per matrix per tile; thread t covers
    // chunk c0 = t and c1 = 512+t (4 chunk-groups per 32-elem row)
    int c0 = t, c1 = 512 + t;
    int r0 = c0 >> 2, g0 = (c0 & 3) ^ ((r0 >> 1) & 3);
    int r1 = c1 >> 2, g1 = (c1 & 3) ^ ((r1 >> 1) & 3);
    const unsigned short* A0 = A + (size_t)(m0 + r0) * D_MODEL + g0 * 8;
    const unsigned short* A1 = A + (size_t)(m0 + r1) * D_MODEL + g1 * 8;
    const unsigned short* B0 = Bt + (size_t)(n0 + r0) * D_MODEL + g0 * 8;
    const unsigned short* B1 = Bt + (size_t)(n0 + r1) * D_MODEL + g1 * 8;
    unsigned short* lA0 = &As[(wave * 64) * 8];
    unsigned short* lA1 = &As[(512 + wave * 64) * 8];
    unsigned short* lB0 = &Bs[(wave * 64) * 8];
    unsigned short* lB1 = &Bs[(512 + wave * 64) * 8];

    // prologue: tile 0 -> buf 0, tile 1 -> buf 1 (4 g2l per tile, FIFO order)
    g2l16(A0, lA0);
    g2l16(A1, lA1);
    g2l16(B0, lB0);
    g2l16(B1, lB1);
    g2l16(A0 + 32, lA0 + GBUF2);
    g2l16(A1 + 32, lA1 + GBUF2);
    g2l16(B0 + 32, lB0 + GBUF2);
    g2l16(B1 + 32, lB1 + GBUF2);

    int bufA = 0, bufB = GBUF2, bufC = 2 * GBUF2;   // kt, kt+1, kt+2 buffers

    for (int kt = 0; kt < NKT - 1; ++kt) {
        // wait for tile kt's 4 loads only; tile kt+1's ride across the barrier
        asm volatile("s_waitcnt vmcnt(4)\n\ts_barrier" ::: "memory");
        __builtin_amdgcn_sched_barrier(0);
        if (kt + 2 < NKT) {
            int ko = (kt + 2) * 32;
            g2l16(A0 + ko, lA0 + bufC);
            g2l16(A1 + ko, lA1 + bufC);
            g2l16(B0 + ko, lB0 + bufC);
            g2l16(B1 + ko, lB1 + bufC);
        }
        bfrag bf[4];
#pragma unroll
        for (int ni = 0; ni < 4; ni++) {
            int row = wc + ni * 16 + lrow;
            bf[ni] = ld_frag(&Bs[bufA + row * 32 + ((quad ^ ((row >> 1) & 3)) * 8)]);
        }
#pragma unroll
        for (int mi = 0; mi < 8; mi++) {
            int row = wr + mi * 16 + lrow;
            bfrag a = ld_frag(&As[bufA + row * 32 + ((quad ^ ((row >> 1) & 3)) * 8)]);
#pragma unroll
            for (int ni = 0; ni < 4; ni++)
                acc[mi][ni] = __builtin_amdgcn_mfma_f32_16x16x32_bf16(a, bf[ni], acc[mi][ni], 0, 0, 0);
        }
        int tmp = bufA; bufA = bufB; bufB = bufC; bufC = tmp;
    }
    // peeled last tile: only its own 4 loads outstanding -> full drain
    asm volatile("s_waitcnt vmcnt(0)\n\ts_barrier" ::: "memory");
    __builtin_amdgcn_sched_barrier(0);
    {
        bfrag bf[4];
#pragma unroll
        for (int ni = 0; ni < 4; ni++) {
            int row = wc + ni * 16 + lrow;
            bf[ni] = ld_frag(&Bs[bufA + row * 32 + ((quad ^ ((row >> 1) & 3)) * 8)]);
        }
#pragma unroll
        for (int mi = 0; mi < 8; mi++) {
            int row = wr + mi * 16 + lrow;
            bfrag a = ld_frag(&As[bufA + row * 32 + ((quad ^ ((row >> 1) & 3)) * 8)]);
#pragma unroll
            for (int ni = 0; ni < 4; ni++)
                acc[mi][ni] = __builtin_amdgcn_mfma_f32_16x16x32_bf16(a, bf[ni], acc[mi][ni], 0, 0, 0);
        }
    }

    // epilogue — C element: row = m0+wr+mi*16+quad*4+r, col = n0+wc+ni*16+lrow
    // R16: FULLY UNROLLED (rule #20) — every acc access compile-time-indexed.
#pragma unroll
    for (int mi = 0; mi < 8; mi++) {
        int row = m0 + wr + mi * 16 + quad * 4;
#pragma unroll
        for (int ni = 0; ni < 4; ni++) {
            int col = n0 + wc + ni * 16 + lrow;
#pragma unroll
            for (int r = 0; r < 4; r++) {
                float v = acc[mi][ni][r];
                int m = row + r;
                if (mode == 0) {
                    int matid = col >> 10;
                    int nn = col & 1023;
                    int h = nn >> 6, d = nn & 63;
                    int b = m >> 11, s = m & 2047;
                    size_t bh = (size_t)(b * NH + h);
                    if (matid == 0)      Qb[(bh * S_LEN + s) * HDIM + d] = f2bf(v);
                    else if (matid == 1) Kb[(bh * S_LEN + s) * HDIM + d] = f2bf(v);
                    else                 Vb[(bh * S_LEN + s) * HDIM + d] = f2bf(v);
                } else {
                    Out[(size_t)m * D_MODEL + col] = v + bias[col];
                }
            }
        }
    }
}

// ---------------- flash attention v10 (transposed-S, dbuf, split-q), causal ----------------
// (unchanged from R2 pass: 64-row q chunks, grid (16,64), XCD remap, dbuf
// K/V staging, fixed-shift softmax, ones-MFMA l, LDS-transposed epilogue)
#define SCALE2 0.18033688f  // 1/sqrt(64) * log2(e)
#define CSHIFT 4.0f
#define KVBUF 4096          // elems per K (or V) buffer: 64*64

__global__ __launch_bounds__(256, 4) void attn_kernel(
    const unsigned short* __restrict__ Qb,
    const unsigned short* __restrict__ Kb,
    const unsigned short* __restrict__ Vtb,
    unsigned short* __restrict__ ctxb) {
    __shared__ unsigned short Ks[2 * KVBUF];      // [buf][key][d]  swizzled
    __shared__ unsigned short Vs[2 * KVBUF];      // [buf][d][key]  swizzled
    __shared__ unsigned short Ps[4 * 16 * 64];    // per wave: [q(16)][key(64)] swizzled
    int flat = (int)(blockIdx.y * gridDim.x + blockIdx.x);   // 1024 blocks
    int wid  = (flat & 7) * 128 + (flat >> 3);
    int bx = wid & 15;    // 0..15
    int bh = wid >> 4;    // 0..63
    int t = threadIdx.x;
    int wave = t >> 6, lane = t & 63;
    int quad = lane >> 4, lrow = lane & 15;
    int swz = lrow & 7;
    int ca = (quad ^ swz) * 8;        // physical elem offset of logical chunk quad
    int cb = ca ^ 32;                 // logical chunk quad+4

    union { uint4 u; bfrag b; } one_u;
    one_u.u.x = 0x3F803F80u; one_u.u.y = 0x3F803F80u;
    one_u.u.z = 0x3F803F80u; one_u.u.w = 0x3F803F80u;
    bfrag onef = one_u.b;             // all-ones A-frag for l row-sum MFMA

    const unsigned short* Qg = Qb + (size_t)bh * S_LEN * HDIM;
    const unsigned short* Kg = Kb + (size_t)bh * S_LEN * HDIM;
    const unsigned short* Vg = Vtb + (size_t)bh * HDIM * S_LEN;
    int b = bh >> 4, h = bh & 15;

    // staging chunk assignment (512 chunks per 64x64 tile, 2 per thread)
    int c0 = t, c1 = 256 + t;
    int kr0 = c0 >> 3, kp0 = (c0 & 7) ^ (kr0 & 7);
    int kr1 = c1 >> 3, kp1 = (c1 & 7) ^ (kr1 & 7);
    const unsigned short* pK0 = Kg + (size_t)kr0 * HDIM + kp0 * 8;
    const unsigned short* pK1 = Kg + (size_t)kr1 * HDIM + kp1 * 8;
    const unsigned short* pV0 = Vg + (size_t)kr0 * S_LEN + kp0 * 8;
    const unsigned short* pV1 = Vg + (size_t)kr1 * S_LEN + kp1 * 8;
    unsigned short* lK0 = &Ks[(wave * 64) * 8];
    unsigned short* lK1 = &Ks[(256 + wave * 64) * 8];
    unsigned short* lV0 = &Vs[(wave * 64) * 8];
    unsigned short* lV1 = &Vs[(256 + wave * 64) * 8];
    unsigned short* Pw = &Ps[wave * 16 * 64];

    for (int ph = 0; ph < 2; ph++) {
        int qc = ph == 0 ? (31 - bx) : bx;   // 64-row q chunk index
        int qw = qc * 64 + wave * 16;
        int nk = qc + 1;

        bfrag qf[2];
#pragma unroll
        for (int c = 0; c < 2; c++)
            qf[c] = ld_frag(Qg + (size_t)(qw + lrow) * HDIM + c * 32 + quad * 8);

        ffrag acc[4];
        ffrag acc_l;
        const ffrag fz = {0.f, 0.f, 0.f, 0.f};
#pragma unroll
        for (int d = 0; d < 4; d++) acc[d] = fz;
        acc_l = fz;

        // phase prologue: buffers free (prev phase/kernel-start), preload tile 0
        __syncthreads();
        g2l16(pK0, lK0);
        g2l16(pK1, lK1);
        g2l16(pV0, lV0);
        g2l16(pV1, lV1);

        for (int kt = 0; kt < nk; kt++) {
            int kbase = kt * 64;
            int buf = (kt & 1) * KVBUF;
            __syncthreads();
            if (kt + 1 < nk) {
                int nb = ((kt + 1) & 1) * KVBUF;
                size_t krow_off = (size_t)(kbase + 64) * HDIM;
                g2l16(pK0 + krow_off, lK0 + nb);
                g2l16(pK1 + krow_off, lK1 + nb);
                g2l16(pV0 + kbase + 64, lV0 + nb);
                g2l16(pV1 + kbase + 64, lV1 + nb);
            }

            // ---- S^T = K Q^T ----
            ffrag sf[4];
#pragma unroll
            for (int ki = 0; ki < 4; ki++) {
                int krow = buf + (ki * 16 + lrow) * 64;
                bfrag ka = ld_frag(&Ks[krow + ca]);
                bfrag kb = ld_frag(&Ks[krow + cb]);
                ffrag s = fz;
                s = __builtin_amdgcn_mfma_f32_16x16x32_bf16(ka, qf[0], s, 0, 0, 0);
                s = __builtin_amdgcn_mfma_f32_16x16x32_bf16(kb, qf[1], s, 0, 0, 0);
                sf[ki] = s;
            }

            // ---- fixed-shift softmax (mask only on the diagonal tile) ----
            int qg = qw + lrow;                  // this lane's q
            bool need_mask = (kt == nk - 1);     // block-uniform
            float sv[16];
#pragma unroll
            for (int ki = 0; ki < 4; ki++)
#pragma unroll
                for (int r = 0; r < 4; r++) {
                    float v = sf[ki][r];
                    if (need_mask) {
                        int key = kbase + ki * 16 + quad * 4 + r;
                        v = (key <= qg) ? v : -3.0e38f;
                    }
                    sv[ki * 4 + r] = fast_exp2(__builtin_fmaf(v, SCALE2, -CSHIFT));
                }
            // P store [q][key] swizzled: logical chunk 2ki+(quad>>1)
            int prow = lrow * 64;
#pragma unroll
            for (int ki = 0; ki < 4; ki++) {
                uint2 w2;
                w2.x = pack_bf16(sv[ki * 4 + 0], sv[ki * 4 + 1]);
                w2.y = pack_bf16(sv[ki * 4 + 2], sv[ki * 4 + 3]);
                int pc = ((ki * 2 + (quad >> 1)) ^ swz) * 8 + (quad & 1) * 4;
                *(uint2*)&Pw[prow + pc] = w2;
            }

            // ---- O^T += V^T P^T ----  (Pw wave-private, DS in-order: no barrier)
            bfrag pf0 = ld_frag(&Pw[prow + ca]);
            bfrag pf1 = ld_frag(&Pw[prow + cb]);
            acc_l = __builtin_amdgcn_mfma_f32_16x16x32_bf16(onef, pf0, acc_l, 0, 0, 0);
            acc_l = __builtin_amdgcn_mfma_f32_16x16x32_bf16(onef, pf1, acc_l, 0, 0, 0);
#pragma unroll
            for (int di = 0; di < 4; di++) {
                int vrow = buf + (di * 16 + lrow) * 64;
                bfrag va = ld_frag(&Vs[vrow + ca]);
                bfrag vb = ld_frag(&Vs[vrow + cb]);
                acc[di] = __builtin_amdgcn_mfma_f32_16x16x32_bf16(va, pf0, acc[di], 0, 0, 0);
                acc[di] = __builtin_amdgcn_mfma_f32_16x16x32_bf16(vb, pf1, acc[di], 0, 0, 0);
            }
        }

        // epilogue: transpose O^T -> O via wave-private LDS, coalesced 16B stores.
        float rl = __builtin_amdgcn_rcpf(acc_l[0]);  // all rows equal; lane lrow=q
#pragma unroll
        for (int di = 0; di < 4; di++) {
            uint2 w2;
            w2.x = pack_bf16(acc[di][0] * rl, acc[di][1] * rl);
            w2.y = pack_bf16(acc[di][2] * rl, acc[di][3] * rl);
            *(uint2*)&Pw[lrow * 64 + di * 16 + quad * 4] = w2;
        }
        int ql = lane >> 3, cc = lane & 7;
#pragma unroll
        for (int p = 0; p < 2; p++) {
            uint4 vv = *(uint4*)&Pw[(p * 8 + ql) * 64 + cc * 8];
            int q = qw + p * 8 + ql;
            *(uint4*)(ctxb + ((size_t)b * S_LEN + q) * D_MODEL + h * HDIM + cc * 8) = vv;
        }
    }
}

extern "C" void kernel_launch(void* const* d_in, const int* in_sizes, int n_in,
                              void* d_out, int out_size, void* d_ws, size_t ws_size,
                              hipStream_t stream) {
    const float* x   = (const float*)d_in[0];
    const float* W_q = (const float*)d_in[1];
    const float* W_k = (const float*)d_in[2];
    const float* W_v = (const float*)d_in[3];
    const float* W_o = (const float*)d_in[4];
    const float* b_o = (const float*)d_in[5];
    float* out = (float*)d_out;

    // workspace carve (elems, ushort).  Vb (row-layout V) aliases ctxb:
    // Vb is dead after transpose_v, before attn writes ctxb.
    unsigned short* xb   = (unsigned short*)d_ws;                    // 8192*1024
    unsigned short* Wt   = xb + (size_t)8192 * 1024;                 // 4*1024*1024
    unsigned short* Qb   = Wt + (size_t)4 * 1024 * 1024;             // 64*2048*64
    unsigned short* Kb   = Qb + (size_t)64 * 2048 * 64;
    unsigned short* Vtb  = Kb + (size_t)64 * 2048 * 64;
    unsigned short* ctxb = Vtb + (size_t)64 * 2048 * 64;             // 8192*1024
    unsigned short* Vb   = ctxb;
    unsigned short* Wto  = Wt + (size_t)3 * 1024 * 1024;

    // fused cast + weight transpose (one launch)
    prep_kernel<<<8192, 256, 0, stream>>>(x, W_q, W_k, W_v, W_o, xb, Wt);
    // QKV: M=8192, N=3072 (V written row-layout [s][d]); 256^2 tiles, 512 thr
    gemm_kernel<<<dim3(12, 32), 512, 0, stream>>>(xb, Wt, 0, Qb, Kb, Vb, nullptr, nullptr);
    // V transpose [s][d] -> [d][s]
    transpose_v_kernel<<<dim3(32, 64), 256, 0, stream>>>(Vb, Vtb);
    // attention (split-q: block bx does 64-row chunks 31-bx then bx; 33 tiles each)
    attn_kernel<<<dim3(16, 64), 256, 0, stream>>>(Qb, Kb, Vtb, ctxb);
    // out proj: M=8192, N=1024, + bias; 256^2 tiles, 512 thr
    gemm_kernel<<<dim3(4, 32), 512, 0, stream>>>(ctxb, Wto, 1, nullptr, nullptr, nullptr, out, b_o);
}

// Round 5
// 271.501 us; speedup vs baseline: 1.5191x; 1.1302x over previous
//
#include <hip/hip_runtime.h>
#include <cstdint>

#define S_LEN 2048
#define D_MODEL 1024
#define NH 16
#define HDIM 64
#define BATCH 4

typedef __attribute__((ext_vector_type(8))) __bf16 bfrag;   // 8 bf16 = 4 VGPR
typedef __attribute__((ext_vector_type(4))) float ffrag;    // 4 f32 acc

__device__ __forceinline__ unsigned short f2bf(float f) {
    union { float f; uint32_t u; } v; v.f = f;
    uint32_t u = v.u;
    u += 0x7fff + ((u >> 16) & 1);   // round-to-nearest-even
    return (unsigned short)(u >> 16);
}

__device__ __forceinline__ bfrag ld_frag(const unsigned short* p) {
    union { uint4 u; bfrag b; } x;
    x.u = *(const uint4*)p;
    return x.b;
}

__device__ __forceinline__ float fast_exp2(float x) {
#if __has_builtin(__builtin_amdgcn_exp2f)
    return __builtin_amdgcn_exp2f(x);
#else
    return __expf(x * 0.6931471805599453f);
#endif
}

// pack two f32 -> packed bf16x2 (round-half-up), 3 VALU inst
__device__ __forceinline__ uint32_t pack_bf16(float a, float b) {
    union { float f; uint32_t u; } x, y; x.f = a; y.f = b;
    return __builtin_amdgcn_perm(y.u + 0x8000u, x.u + 0x8000u, 0x07060302u);
}

__device__ __forceinline__ void g2l16(const unsigned short* g, unsigned short* l) {
    __builtin_amdgcn_global_load_lds(
        (const __attribute__((address_space(1))) void*)g,
        (__attribute__((address_space(3))) void*)l, 16, 0, 0);
}

// -------- fused prep: cast x (fp32->bf16) + cast/transpose weights ----------
__global__ __launch_bounds__(256) void prep_kernel(const float* __restrict__ x,
                                                   const float* __restrict__ w0,
                                                   const float* __restrict__ w1,
                                                   const float* __restrict__ w2,
                                                   const float* __restrict__ w3,
                                                   unsigned short* __restrict__ xb,
                                                   unsigned short* __restrict__ wt) {
    __shared__ float tile[32][33];
    int bid = blockIdx.x;
    int t = threadIdx.x;
    if (bid < 4096) {
        int i = bid * 256 + t;
        const float4* p = (const float4*)x + (size_t)i * 2;
        float4 a = p[0], b = p[1];
        union { unsigned short u[8]; uint4 v; } o;
        o.u[0]=f2bf(a.x); o.u[1]=f2bf(a.y); o.u[2]=f2bf(a.z); o.u[3]=f2bf(a.w);
        o.u[4]=f2bf(b.x); o.u[5]=f2bf(b.y); o.u[6]=f2bf(b.z); o.u[7]=f2bf(b.w);
        ((uint4*)xb)[i] = o.v;
    } else {
        int r = bid - 4096;
        int mat = r >> 10;
        int rem = r & 1023;
        const float* w = (mat == 0) ? w0 : (mat == 1) ? w1 : (mat == 2) ? w2 : w3;
        int n0 = (rem & 31) * 32, k0 = (rem >> 5) * 32;
        int tx = t & 31, ty = t >> 5;   // 32 x 8
        for (int i = 0; i < 32; i += 8)
            tile[ty + i][tx] = w[(size_t)(k0 + ty + i) * D_MODEL + n0 + tx];
        __syncthreads();
        unsigned short* o = wt + (size_t)mat * D_MODEL * D_MODEL;
        for (int i = 0; i < 32; i += 8)
            o[(size_t)(n0 + ty + i) * D_MODEL + (k0 + tx)] = f2bf(tile[tx][ty + i]);
    }
}

// ------------- V transpose: Vb[bh][s][d] -> Vtb[bh][d][s] (bf16) -------------
__global__ __launch_bounds__(256) void transpose_v_kernel(const unsigned short* __restrict__ Vb,
                                                          unsigned short* __restrict__ Vtb) {
    __shared__ unsigned short tile[64][72];
    int st = blockIdx.x;   // s-tile of 64
    int bh = blockIdx.y;
    int t = threadIdx.x;
    int sl = t >> 2, dc = (t & 3) * 16;
    const unsigned short* src = Vb + ((size_t)bh * S_LEN + st * 64 + sl) * HDIM + dc;
    *(uint4*)&tile[sl][dc]     = *(const uint4*)(src);
    *(uint4*)&tile[sl][dc + 8] = *(const uint4*)(src + 8);
    __syncthreads();
    int d = t >> 2, sc = (t & 3) * 16;
    union { unsigned short u[16]; uint4 v[2]; } o;
#pragma unroll
    for (int i = 0; i < 16; i++) o.u[i] = tile[sc + i][d];
    unsigned short* dst = Vtb + ((size_t)bh * HDIM + d) * S_LEN + st * 64 + sc;
    *(uint4*)(dst)     = o.v[0];
    *(uint4*)(dst + 8) = o.v[1];
}

#define MFMA_BF16 __builtin_amdgcn_mfma_f32_16x16x32_bf16

// ============ gemm256: QKV GEMM, 256x256 tile, 4-deep ring, phase-split ======
// R17: the R2/R4 counters proved the 2-phase family ceiling (~500-530 TF,
// MfmaUtil 19-22%, all pipes idle; == documented 2ph cap). This kernel is the
// phase-split schedule (T3+T4 -> T5): per K-tile (BK=32):
//   s_waitcnt vmcnt(8); s_barrier   (tiles kt+1,kt+2 stay in flight ACROSS
//   the barrier -> 2+ iters latency budget); stage kt+3 into 4-slot ring;
//   phase0 {12 ds_read_b128 -> lgkmcnt(0)+sched_barrier -> setprio(1) ->
//   16 MFMA (mi0-3) -> setprio(0)}; phase1 {4 ds_read (mi4-7) -> ... 16 MFMA}.
// Ring-safety: tile kt+3 overwrites slot of tile kt-1; all waves passed this
// iteration's barrier => their kt-1 ds_reads retired (lgkmcnt(0) precedes
// their MFMAs which precede the barrier). vmcnt(8) = 2 tiles (4 wave-inst
// each) outstanding. Tails peeled at vmcnt(4)/vmcnt(0); staging stops at
// tile 31 (guard kt<29) -> no OOB reads.
// LDS 128 KB = 4 x (16K A + 16K B). 1 block/CU, 8 waves (2M x 4N), wave tile
// 128x64, acc[8][4]=128 f32 (AGPR). Epilogue = R16 fully-unrolled (rule #20).
#define QBUF 8192   // elems per matrix per ring slot: 256 rows * 32
#define NKT  (D_MODEL / 32)   // 32 k-tiles

// one K-tile: 2 phases, B frags shared across both
#define Q_TILE(bufA)                                                              \
  do {                                                                            \
    bfrag bf_[4], af_[4];                                                         \
    _Pragma("unroll")                                                             \
    for (int ni = 0; ni < 4; ni++) {                                              \
      int row = wc + ni * 16 + lrow;                                              \
      bf_[ni] = ld_frag(&Bs[(bufA) + row * 32 + ((quad ^ ((row >> 1) & 3)) * 8)]);\
    }                                                                             \
    _Pragma("unroll")                                                             \
    for (int mi = 0; mi < 4; mi++) {                                              \
      int row = wr + mi * 16 + lrow;                                              \
      af_[mi] = ld_frag(&As[(bufA) + row * 32 + ((quad ^ ((row >> 1) & 3)) * 8)]);\
    }                                                                             \
    asm volatile("s_waitcnt lgkmcnt(0)" ::: "memory");                            \
    __builtin_amdgcn_sched_barrier(0);                                            \
    __builtin_amdgcn_s_setprio(1);                                                \
    _Pragma("unroll")                                                             \
    for (int mi = 0; mi < 4; mi++)                                                \
      _Pragma("unroll")                                                           \
      for (int ni = 0; ni < 4; ni++)                                              \
        acc[mi][ni] = MFMA_BF16(af_[mi], bf_[ni], acc[mi][ni], 0, 0, 0);          \
    __builtin_amdgcn_s_setprio(0);                                                \
    __builtin_amdgcn_sched_barrier(0);                                            \
    _Pragma("unroll")                                                             \
    for (int mi = 0; mi < 4; mi++) {                                              \
      int row = wr + (mi + 4) * 16 + lrow;                                        \
      af_[mi] = ld_frag(&As[(bufA) + row * 32 + ((quad ^ ((row >> 1) & 3)) * 8)]);\
    }                                                                             \
    asm volatile("s_waitcnt lgkmcnt(0)" ::: "memory");                            \
    __builtin_amdgcn_sched_barrier(0);                                            \
    __builtin_amdgcn_s_setprio(1);                                                \
    _Pragma("unroll")                                                             \
    for (int mi = 0; mi < 4; mi++)                                                \
      _Pragma("unroll")                                                           \
      for (int ni = 0; ni < 4; ni++)                                              \
        acc[mi + 4][ni] = MFMA_BF16(af_[mi], bf_[ni], acc[mi + 4][ni], 0, 0, 0);  \
    __builtin_amdgcn_s_setprio(0);                                                \
  } while (0)

__global__ __launch_bounds__(512, 2) void gemm256_kernel(
    const unsigned short* __restrict__ A,
    const unsigned short* __restrict__ Bt,
    unsigned short* __restrict__ Qb,
    unsigned short* __restrict__ Kb,
    unsigned short* __restrict__ Vb) {
    __shared__ unsigned short As[4 * QBUF];
    __shared__ unsigned short Bs[4 * QBUF];
    int t = threadIdx.x;

    // T1: XCD-aware remap (bijective: nwg = 384, % 8 == 0)
    int gx   = (int)gridDim.x;
    int nwg  = gx * (int)gridDim.y;
    int flat = (int)(blockIdx.y * gridDim.x + blockIdx.x);
    int cpx  = nwg >> 3;
    int wid  = (flat & 7) * cpx + (flat >> 3);
    int m0 = (wid / gx) * 256;
    int n0 = (wid % gx) * 256;

    int wave = t >> 6, lane = t & 63;
    int quad = lane >> 4, lrow = lane & 15;
    int wr = (wave & 1) * 128;    // M offset of wave tile
    int wc = (wave >> 1) * 64;    // N offset of wave tile

    ffrag acc[8][4];
    const ffrag fz = {0.f, 0.f, 0.f, 0.f};
#pragma unroll
    for (int i = 0; i < 8; i++)
#pragma unroll
        for (int j = 0; j < 4; j++) acc[i][j] = fz;

    // staging: 1024 chunks of 8 elems per matrix per tile; thread t covers
    // chunk c0 = t (rows 0-127) and c1 = 512+t (rows 128-255); XOR group swz
    int c0 = t, c1 = 512 + t;
    int r0 = c0 >> 2, g0 = (c0 & 3) ^ ((r0 >> 1) & 3);
    int r1 = c1 >> 2, g1 = (c1 & 3) ^ ((r1 >> 1) & 3);
    const unsigned short* A0 = A + (size_t)(m0 + r0) * D_MODEL + g0 * 8;
    const unsigned short* A1 = A + (size_t)(m0 + r1) * D_MODEL + g1 * 8;
    const unsigned short* B0 = Bt + (size_t)(n0 + r0) * D_MODEL + g0 * 8;
    const unsigned short* B1 = Bt + (size_t)(n0 + r1) * D_MODEL + g1 * 8;
    unsigned short* lA0 = &As[(wave * 64) * 8];
    unsigned short* lA1 = &As[(512 + wave * 64) * 8];
    unsigned short* lB0 = &Bs[(wave * 64) * 8];
    unsigned short* lB1 = &Bs[(512 + wave * 64) * 8];

    // prologue: tiles 0,1,2 -> ring slots 0,1,2 (FIFO, 4 wave-inst per tile)
    g2l16(A0, lA0);
    g2l16(A1, lA1);
    g2l16(B0, lB0);
    g2l16(B1, lB1);
    g2l16(A0 + 32, lA0 + QBUF);
    g2l16(A1 + 32, lA1 + QBUF);
    g2l16(B0 + 32, lB0 + QBUF);
    g2l16(B1 + 32, lB1 + QBUF);
    g2l16(A0 + 64, lA0 + 2 * QBUF);
    g2l16(A1 + 64, lA1 + 2 * QBUF);
    g2l16(B0 + 64, lB0 + 2 * QBUF);
    g2l16(B1 + 64, lB1 + 2 * QBUF);

    for (int kt = 0; kt < NKT - 2; ++kt) {
        // tile kt must be landed; kt+1, kt+2 (8 wave-inst) ride across barrier
        asm volatile("s_waitcnt vmcnt(8)\n\ts_barrier" ::: "memory");
        __builtin_amdgcn_sched_barrier(0);
        if (kt < NKT - 3) {   // stage tile kt+3 into slot (kt+3)&3 (= kt-1's)
            int ko = (kt + 3) * 32;
            int nb = ((kt + 3) & 3) * QBUF;
            g2l16(A0 + ko, lA0 + nb);
            g2l16(A1 + ko, lA1 + nb);
            g2l16(B0 + ko, lB0 + nb);
            g2l16(B1 + ko, lB1 + nb);
        }
        int bufA = (kt & 3) * QBUF;
        Q_TILE(bufA);
    }
    {   // kt = NKT-2: only tile NKT-1 (4 inst) may remain in flight
        asm volatile("s_waitcnt vmcnt(4)\n\ts_barrier" ::: "memory");
        __builtin_amdgcn_sched_barrier(0);
        int bufA = ((NKT - 2) & 3) * QBUF;
        Q_TILE(bufA);
    }
    {   // kt = NKT-1: full drain
        asm volatile("s_waitcnt vmcnt(0)\n\ts_barrier" ::: "memory");
        __builtin_amdgcn_sched_barrier(0);
        int bufA = ((NKT - 1) & 3) * QBUF;
        Q_TILE(bufA);
    }

    // epilogue — QKV scatter; fully unrolled (rule #20, R16 lesson)
#pragma unroll
    for (int mi = 0; mi < 8; mi++) {
        int row = m0 + wr + mi * 16 + quad * 4;
#pragma unroll
        for (int ni = 0; ni < 4; ni++) {
            int col = n0 + wc + ni * 16 + lrow;
#pragma unroll
            for (int r = 0; r < 4; r++) {
                float v = acc[mi][ni][r];
                int m = row + r;
                int matid = col >> 10;
                int nn = col & 1023;
                int h = nn >> 6, d = nn & 63;
                int b = m >> 11, s = m & 2047;
                size_t bh = (size_t)(b * NH + h);
                if (matid == 0)      Qb[(bh * S_LEN + s) * HDIM + d] = f2bf(v);
                else if (matid == 1) Kb[(bh * S_LEN + s) * HDIM + d] = f2bf(v);
                else                 Vb[(bh * S_LEN + s) * HDIM + d] = f2bf(v);
            }
        }
    }
}

// ============ gemm128: out-proj GEMM (R2-proven 128x128 triple-buffer) ======
// Byte-identical structure to the R2 pass (96.8us QKV / ~35us out-proj):
// triple-buffered, 2-deep prefetch, s_waitcnt vmcnt(4)+s_barrier fused.
#define GBUF 4096   // elems per A (or B) buffer: 128*32

__global__ __launch_bounds__(256) void gemm128_kernel(
    const unsigned short* __restrict__ A,
    const unsigned short* __restrict__ Bt,
    float* __restrict__ Out,
    const float* __restrict__ bias) {
    __shared__ unsigned short As[3 * GBUF];
    __shared__ unsigned short Bs[3 * GBUF];
    int t = threadIdx.x;

    // T1: XCD-aware remap (bijective: nwg = 512, % 8 == 0)
    int nwg  = (int)(gridDim.x * gridDim.y);
    int flat = (int)(blockIdx.y * gridDim.x + blockIdx.x);
    int cpx  = nwg >> 3;
    int wid  = (flat & 7) * cpx + (flat >> 3);
    int m0 = (wid / (int)gridDim.x) * 128;
    int n0 = (wid % (int)gridDim.x) * 128;

    int wave = t >> 6, lane = t & 63;
    int quad = lane >> 4, lrow = lane & 15;
    int wm = (wave & 1) * 64, wn = (wave >> 1) * 64;

    ffrag acc[4][4];
    const ffrag fz = {0.f, 0.f, 0.f, 0.f};
    for (int i = 0; i < 4; i++)
        for (int j = 0; j < 4; j++) acc[i][j] = fz;

    int c0 = t, c1 = 256 + t;
    int r0 = c0 >> 2, cg0 = (c0 & 3) ^ ((r0 >> 1) & 3);
    int r1 = c1 >> 2, cg1 = (c1 & 3) ^ ((r1 >> 1) & 3);
    const unsigned short* A0 = A + (size_t)(m0 + r0) * D_MODEL + cg0 * 8;
    const unsigned short* A1 = A + (size_t)(m0 + r1) * D_MODEL + cg1 * 8;
    const unsigned short* B0 = Bt + (size_t)(n0 + r0) * D_MODEL + cg0 * 8;
    const unsigned short* B1 = Bt + (size_t)(n0 + r1) * D_MODEL + cg1 * 8;
    unsigned short* lA0 = &As[(wave * 64) * 8];
    unsigned short* lA1 = &As[(256 + wave * 64) * 8];
    unsigned short* lB0 = &Bs[(wave * 64) * 8];
    unsigned short* lB1 = &Bs[(256 + wave * 64) * 8];

    g2l16(A0, lA0);
    g2l16(A1, lA1);
    g2l16(B0, lB0);
    g2l16(B1, lB1);
    g2l16(A0 + 32, lA0 + GBUF);
    g2l16(A1 + 32, lA1 + GBUF);
    g2l16(B0 + 32, lB0 + GBUF);
    g2l16(B1 + 32, lB1 + GBUF);

    int bufA = 0, bufB = GBUF, bufC = 2 * GBUF;

    for (int kt = 0; kt < NKT - 1; ++kt) {
        asm volatile("s_waitcnt vmcnt(4)\n\ts_barrier" ::: "memory");
        __builtin_amdgcn_sched_barrier(0);
        if (kt + 2 < NKT) {
            int ko = (kt + 2) * 32;
            g2l16(A0 + ko, lA0 + bufC);
            g2l16(A1 + ko, lA1 + bufC);
            g2l16(B0 + ko, lB0 + bufC);
            g2l16(B1 + ko, lB1 + bufC);
        }
        bfrag af[4], bf[4];
        for (int mi = 0; mi < 4; mi++) {
            int row = wm + mi * 16 + lrow;
            af[mi] = ld_frag(&As[bufA + row * 32 + ((quad ^ ((row >> 1) & 3)) * 8)]);
        }
        for (int ni = 0; ni < 4; ni++) {
            int row = wn + ni * 16 + lrow;
            bf[ni] = ld_frag(&Bs[bufA + row * 32 + ((quad ^ ((row >> 1) & 3)) * 8)]);
        }
        for (int mi = 0; mi < 4; mi++)
            for (int ni = 0; ni < 4; ni++)
                acc[mi][ni] = MFMA_BF16(af[mi], bf[ni], acc[mi][ni], 0, 0, 0);
        int tmp = bufA; bufA = bufB; bufB = bufC; bufC = tmp;
    }
    asm volatile("s_waitcnt vmcnt(0)\n\ts_barrier" ::: "memory");
    __builtin_amdgcn_sched_barrier(0);
    {
        bfrag af[4], bf[4];
        for (int mi = 0; mi < 4; mi++) {
            int row = wm + mi * 16 + lrow;
            af[mi] = ld_frag(&As[bufA + row * 32 + ((quad ^ ((row >> 1) & 3)) * 8)]);
        }
        for (int ni = 0; ni < 4; ni++) {
            int row = wn + ni * 16 + lrow;
            bf[ni] = ld_frag(&Bs[bufA + row * 32 + ((quad ^ ((row >> 1) & 3)) * 8)]);
        }
        for (int mi = 0; mi < 4; mi++)
            for (int ni = 0; ni < 4; ni++)
                acc[mi][ni] = MFMA_BF16(af[mi], bf[ni], acc[mi][ni], 0, 0, 0);
    }

#pragma unroll
    for (int mi = 0; mi < 4; mi++) {
        int row = m0 + wm + mi * 16 + quad * 4;
#pragma unroll
        for (int ni = 0; ni < 4; ni++) {
            int col = n0 + wn + ni * 16 + lrow;
#pragma unroll
            for (int r = 0; r < 4; r++) {
                int m = row + r;
                Out[(size_t)m * D_MODEL + col] = acc[mi][ni][r] + bias[col];
            }
        }
    }
}

// ---------------- flash attention v10 (unchanged from R2/R4 pass) ----------------
#define SCALE2 0.18033688f  // 1/sqrt(64) * log2(e)
#define CSHIFT 4.0f
#define KVBUF 4096          // elems per K (or V) buffer: 64*64

__global__ __launch_bounds__(256, 4) void attn_kernel(
    const unsigned short* __restrict__ Qb,
    const unsigned short* __restrict__ Kb,
    const unsigned short* __restrict__ Vtb,
    unsigned short* __restrict__ ctxb) {
    __shared__ unsigned short Ks[2 * KVBUF];      // [buf][key][d]  swizzled
    __shared__ unsigned short Vs[2 * KVBUF];      // [buf][d][key]  swizzled
    __shared__ unsigned short Ps[4 * 16 * 64];    // per wave: [q(16)][key(64)] swizzled
    int flat = (int)(blockIdx.y * gridDim.x + blockIdx.x);   // 1024 blocks
    int wid  = (flat & 7) * 128 + (flat >> 3);
    int bx = wid & 15;    // 0..15
    int bh = wid >> 4;    // 0..63
    int t = threadIdx.x;
    int wave = t >> 6, lane = t & 63;
    int quad = lane >> 4, lrow = lane & 15;
    int swz = lrow & 7;
    int ca = (quad ^ swz) * 8;        // physical elem offset of logical chunk quad
    int cb = ca ^ 32;                 // logical chunk quad+4

    union { uint4 u; bfrag b; } one_u;
    one_u.u.x = 0x3F803F80u; one_u.u.y = 0x3F803F80u;
    one_u.u.z = 0x3F803F80u; one_u.u.w = 0x3F803F80u;
    bfrag onef = one_u.b;             // all-ones A-frag for l row-sum MFMA

    const unsigned short* Qg = Qb + (size_t)bh * S_LEN * HDIM;
    const unsigned short* Kg = Kb + (size_t)bh * S_LEN * HDIM;
    const unsigned short* Vg = Vtb + (size_t)bh * HDIM * S_LEN;
    int b = bh >> 4, h = bh & 15;

    int c0 = t, c1 = 256 + t;
    int kr0 = c0 >> 3, kp0 = (c0 & 7) ^ (kr0 & 7);
    int kr1 = c1 >> 3, kp1 = (c1 & 7) ^ (kr1 & 7);
    const unsigned short* pK0 = Kg + (size_t)kr0 * HDIM + kp0 * 8;
    const unsigned short* pK1 = Kg + (size_t)kr1 * HDIM + kp1 * 8;
    const unsigned short* pV0 = Vg + (size_t)kr0 * S_LEN + kp0 * 8;
    const unsigned short* pV1 = Vg + (size_t)kr1 * S_LEN + kp1 * 8;
    unsigned short* lK0 = &Ks[(wave * 64) * 8];
    unsigned short* lK1 = &Ks[(256 + wave * 64) * 8];
    unsigned short* lV0 = &Vs[(wave * 64) * 8];
    unsigned short* lV1 = &Vs[(256 + wave * 64) * 8];
    unsigned short* Pw = &Ps[wave * 16 * 64];

    for (int ph = 0; ph < 2; ph++) {
        int qc = ph == 0 ? (31 - bx) : bx;   // 64-row q chunk index
        int qw = qc * 64 + wave * 16;
        int nk = qc + 1;

        bfrag qf[2];
#pragma unroll
        for (int c = 0; c < 2; c++)
            qf[c] = ld_frag(Qg + (size_t)(qw + lrow) * HDIM + c * 32 + quad * 8);

        ffrag acc[4];
        ffrag acc_l;
        const ffrag fz = {0.f, 0.f, 0.f, 0.f};
#pragma unroll
        for (int d = 0; d < 4; d++) acc[d] = fz;
        acc_l = fz;

        __syncthreads();
        g2l16(pK0, lK0);
        g2l16(pK1, lK1);
        g2l16(pV0, lV0);
        g2l16(pV1, lV1);

        for (int kt = 0; kt < nk; kt++) {
            int kbase = kt * 64;
            int buf = (kt & 1) * KVBUF;
            __syncthreads();
            if (kt + 1 < nk) {
                int nb = ((kt + 1) & 1) * KVBUF;
                size_t krow_off = (size_t)(kbase + 64) * HDIM;
                g2l16(pK0 + krow_off, lK0 + nb);
                g2l16(pK1 + krow_off, lK1 + nb);
                g2l16(pV0 + kbase + 64, lV0 + nb);
                g2l16(pV1 + kbase + 64, lV1 + nb);
            }

            // ---- S^T = K Q^T ----
            ffrag sf[4];
#pragma unroll
            for (int ki = 0; ki < 4; ki++) {
                int krow = buf + (ki * 16 + lrow) * 64;
                bfrag ka = ld_frag(&Ks[krow + ca]);
                bfrag kb = ld_frag(&Ks[krow + cb]);
                ffrag s = fz;
                s = __builtin_amdgcn_mfma_f32_16x16x32_bf16(ka, qf[0], s, 0, 0, 0);
                s = __builtin_amdgcn_mfma_f32_16x16x32_bf16(kb, qf[1], s, 0, 0, 0);
                sf[ki] = s;
            }

            // ---- fixed-shift softmax (mask only on the diagonal tile) ----
            int qg = qw + lrow;                  // this lane's q
            bool need_mask = (kt == nk - 1);     // block-uniform
            float sv[16];
#pragma unroll
            for (int ki = 0; ki < 4; ki++)
#pragma unroll
                for (int r = 0; r < 4; r++) {
                    float v = sf[ki][r];
                    if (need_mask) {
                        int key = kbase + ki * 16 + quad * 4 + r;
                        v = (key <= qg) ? v : -3.0e38f;
                    }
                    sv[ki * 4 + r] = fast_exp2(__builtin_fmaf(v, SCALE2, -CSHIFT));
                }
            int prow = lrow * 64;
#pragma unroll
            for (int ki = 0; ki < 4; ki++) {
                uint2 w2;
                w2.x = pack_bf16(sv[ki * 4 + 0], sv[ki * 4 + 1]);
                w2.y = pack_bf16(sv[ki * 4 + 2], sv[ki * 4 + 3]);
                int pc = ((ki * 2 + (quad >> 1)) ^ swz) * 8 + (quad & 1) * 4;
                *(uint2*)&Pw[prow + pc] = w2;
            }

            // ---- O^T += V^T P^T ----  (Pw wave-private, DS in-order: no barrier)
            bfrag pf0 = ld_frag(&Pw[prow + ca]);
            bfrag pf1 = ld_frag(&Pw[prow + cb]);
            acc_l = __builtin_amdgcn_mfma_f32_16x16x32_bf16(onef, pf0, acc_l, 0, 0, 0);
            acc_l = __builtin_amdgcn_mfma_f32_16x16x32_bf16(onef, pf1, acc_l, 0, 0, 0);
#pragma unroll
            for (int di = 0; di < 4; di++) {
                int vrow = buf + (di * 16 + lrow) * 64;
                bfrag va = ld_frag(&Vs[vrow + ca]);
                bfrag vb = ld_frag(&Vs[vrow + cb]);
                acc[di] = __builtin_amdgcn_mfma_f32_16x16x32_bf16(va, pf0, acc[di], 0, 0, 0);
                acc[di] = __builtin_amdgcn_mfma_f32_16x16x32_bf16(vb, pf1, acc[di], 0, 0, 0);
            }
        }

        // epilogue: transpose O^T -> O via wave-private LDS, coalesced 16B stores.
        float rl = __builtin_amdgcn_rcpf(acc_l[0]);  // all rows equal; lane lrow=q
#pragma unroll
        for (int di = 0; di < 4; di++) {
            uint2 w2;
            w2.x = pack_bf16(acc[di][0] * rl, acc[di][1] * rl);
            w2.y = pack_bf16(acc[di][2] * rl, acc[di][3] * rl);
            *(uint2*)&Pw[lrow * 64 + di * 16 + quad * 4] = w2;
        }
        int ql = lane >> 3, cc = lane & 7;
#pragma unroll
        for (int p = 0; p < 2; p++) {
            uint4 vv = *(uint4*)&Pw[(p * 8 + ql) * 64 + cc * 8];
            int q = qw + p * 8 + ql;
            *(uint4*)(ctxb + ((size_t)b * S_LEN + q) * D_MODEL + h * HDIM + cc * 8) = vv;
        }
    }
}

extern "C" void kernel_launch(void* const* d_in, const int* in_sizes, int n_in,
                              void* d_out, int out_size, void* d_ws, size_t ws_size,
                              hipStream_t stream) {
    const float* x   = (const float*)d_in[0];
    const float* W_q = (const float*)d_in[1];
    const float* W_k = (const float*)d_in[2];
    const float* W_v = (const float*)d_in[3];
    const float* W_o = (const float*)d_in[4];
    const float* b_o = (const float*)d_in[5];
    float* out = (float*)d_out;

    // workspace carve (elems, ushort).  Vb (row-layout V) aliases ctxb:
    // Vb is dead after transpose_v, before attn writes ctxb.
    unsigned short* xb   = (unsigned short*)d_ws;                    // 8192*1024
    unsigned short* Wt   = xb + (size_t)8192 * 1024;                 // 4*1024*1024
    unsigned short* Qb   = Wt + (size_t)4 * 1024 * 1024;             // 64*2048*64
    unsigned short* Kb   = Qb + (size_t)64 * 2048 * 64;
    unsigned short* Vtb  = Kb + (size_t)64 * 2048 * 64;
    unsigned short* ctxb = Vtb + (size_t)64 * 2048 * 64;             // 8192*1024
    unsigned short* Vb   = ctxb;
    unsigned short* Wto  = Wt + (size_t)3 * 1024 * 1024;

    // fused cast + weight transpose (one launch)
    prep_kernel<<<8192, 256, 0, stream>>>(x, W_q, W_k, W_v, W_o, xb, Wt);
    // QKV: M=8192, N=3072; 256^2 tiles, 512 thr, phase-split ring schedule
    gemm256_kernel<<<dim3(12, 32), 512, 0, stream>>>(xb, Wt, Qb, Kb, Vb);
    // V transpose [s][d] -> [d][s]
    transpose_v_kernel<<<dim3(32, 64), 256, 0, stream>>>(Vb, Vtb);
    // attention (split-q: block bx does 64-row chunks 31-bx then bx; 33 tiles each)
    attn_kernel<<<dim3(16, 64), 256, 0, stream>>>(Qb, Kb, Vtb, ctxb);
    // out proj: M=8192, N=1024, + bias; R2-proven 128^2 kernel, 512 blocks
    gemm128_kernel<<<dim3(8, 64), 256, 0, stream>>>(ctxb, Wto, out, b_o);
}

// Round 6
// 267.791 us; speedup vs baseline: 1.5402x; 1.0139x over previous
//
#include <hip/hip_runtime.h>
#include <cstdint>

#define S_LEN 2048
#define D_MODEL 1024
#define NH 16
#define HDIM 64
#define BATCH 4

typedef __attribute__((ext_vector_type(8))) __bf16 bfrag;   // 8 bf16 = 4 VGPR
typedef __attribute__((ext_vector_type(4))) float ffrag;    // 4 f32 acc

__device__ __forceinline__ unsigned short f2bf(float f) {
    union { float f; uint32_t u; } v; v.f = f;
    uint32_t u = v.u;
    u += 0x7fff + ((u >> 16) & 1);   // round-to-nearest-even
    return (unsigned short)(u >> 16);
}

__device__ __forceinline__ bfrag ld_frag(const unsigned short* p) {
    union { uint4 u; bfrag b; } x;
    x.u = *(const uint4*)p;
    return x.b;
}

__device__ __forceinline__ float fast_exp2(float x) {
#if __has_builtin(__builtin_amdgcn_exp2f)
    return __builtin_amdgcn_exp2f(x);
#else
    return __expf(x * 0.6931471805599453f);
#endif
}

// pack two f32 -> packed bf16x2 (round-half-up), 3 VALU inst
__device__ __forceinline__ uint32_t pack_bf16(float a, float b) {
    union { float f; uint32_t u; } x, y; x.f = a; y.f = b;
    return __builtin_amdgcn_perm(y.u + 0x8000u, x.u + 0x8000u, 0x07060302u);
}

__device__ __forceinline__ void g2l16(const unsigned short* g, unsigned short* l) {
    __builtin_amdgcn_global_load_lds(
        (const __attribute__((address_space(1))) void*)g,
        (__attribute__((address_space(3))) void*)l, 16, 0, 0);
}

// -------- fused prep: cast x (fp32->bf16) + cast/transpose weights ----------
__global__ __launch_bounds__(256) void prep_kernel(const float* __restrict__ x,
                                                   const float* __restrict__ w0,
                                                   const float* __restrict__ w1,
                                                   const float* __restrict__ w2,
                                                   const float* __restrict__ w3,
                                                   unsigned short* __restrict__ xb,
                                                   unsigned short* __restrict__ wt) {
    __shared__ float tile[32][33];
    int bid = blockIdx.x;
    int t = threadIdx.x;
    if (bid < 4096) {
        int i = bid * 256 + t;
        const float4* p = (const float4*)x + (size_t)i * 2;
        float4 a = p[0], b = p[1];
        union { unsigned short u[8]; uint4 v; } o;
        o.u[0]=f2bf(a.x); o.u[1]=f2bf(a.y); o.u[2]=f2bf(a.z); o.u[3]=f2bf(a.w);
        o.u[4]=f2bf(b.x); o.u[5]=f2bf(b.y); o.u[6]=f2bf(b.z); o.u[7]=f2bf(b.w);
        ((uint4*)xb)[i] = o.v;
    } else {
        int r = bid - 4096;
        int mat = r >> 10;
        int rem = r & 1023;
        const float* w = (mat == 0) ? w0 : (mat == 1) ? w1 : (mat == 2) ? w2 : w3;
        int n0 = (rem & 31) * 32, k0 = (rem >> 5) * 32;
        int tx = t & 31, ty = t >> 5;   // 32 x 8
        for (int i = 0; i < 32; i += 8)
            tile[ty + i][tx] = w[(size_t)(k0 + ty + i) * D_MODEL + n0 + tx];
        __syncthreads();
        unsigned short* o = wt + (size_t)mat * D_MODEL * D_MODEL;
        for (int i = 0; i < 32; i += 8)
            o[(size_t)(n0 + ty + i) * D_MODEL + (k0 + tx)] = f2bf(tile[tx][ty + i]);
    }
}

// ------------- V transpose: Vb[bh][s][d] -> Vtb[bh][d][s] (bf16) -------------
__global__ __launch_bounds__(256) void transpose_v_kernel(const unsigned short* __restrict__ Vb,
                                                          unsigned short* __restrict__ Vtb) {
    __shared__ unsigned short tile[64][72];
    int st = blockIdx.x;   // s-tile of 64
    int bh = blockIdx.y;
    int t = threadIdx.x;
    int sl = t >> 2, dc = (t & 3) * 16;
    const unsigned short* src = Vb + ((size_t)bh * S_LEN + st * 64 + sl) * HDIM + dc;
    *(uint4*)&tile[sl][dc]     = *(const uint4*)(src);
    *(uint4*)&tile[sl][dc + 8] = *(const uint4*)(src + 8);
    __syncthreads();
    int d = t >> 2, sc = (t & 3) * 16;
    union { unsigned short u[16]; uint4 v[2]; } o;
#pragma unroll
    for (int i = 0; i < 16; i++) o.u[i] = tile[sc + i][d];
    unsigned short* dst = Vtb + ((size_t)bh * HDIM + d) * S_LEN + st * 64 + sc;
    *(uint4*)(dst)     = o.v[0];
    *(uint4*)(dst + 8) = o.v[1];
}

#define MFMA_BF16 __builtin_amdgcn_mfma_f32_16x16x32_bf16

// ========== GEMM: C[M][N] = A[M][K=1024] * Bt[N][K]^T, 256x128 tile =========
// R18: counters (R5: Occupancy 15.4%, 1 blk/CU, 2 waves/SIMD, MfmaUtil 22.5%)
// showed wave starvation + packing quantization (384 blks, 1/CU -> 2 rounds,
// half machine idle in round 2). This round: SMALLER blocks, MORE of them:
//  - 256x128 tile, 512 thr, 8 waves (4M x 2N), wave tile 64x64, acc[4][4]=64
//    AGPR + ~56 arch VGPR -> total ~120 <= 128 => 4 waves/SIMD, 2 blocks/CU
//    (__launch_bounds__(512,4): w=4 waves/EU -> k = 4*4/8 = 2 blocks/CU).
//  - LDS ring-3 x (16K A + 8K B) = 72 KB -> 2 blocks/CU fit (144 <= 160).
//  - QKV grid = 32x24 = 768 blocks (%8==0, continuous 1.5-round packing at
//    2/CU); out-proj = 256 blocks = exactly 1/CU.
//  - sync skeleton = twice-proven counted-vmcnt ring: per tile
//    "s_waitcnt vmcnt(3); s_barrier" fused, stage kt+2 (3 g2l16/thread),
//    body, rotate; tail peeled at vmcnt(0). Cross-block anti-phase (m114)
//    supplies the MFMA/load overlap that single-block lockstep couldn't.
// Spill tripwire (R3 lesson): if WRITE_SIZE >> 50 MB, the 128-reg cap
// spilled -> revert launch_bounds to (512,2) next round.
#define AS_SLOT 8192    // 256 rows * 32 elems
#define BS_SLOT 4096    // 128 rows * 32 elems
#define NKT  (D_MODEL / 32)   // 32 k-tiles

__global__ __launch_bounds__(512, 4) void gemm_kernel(
    const unsigned short* __restrict__ A,
    const unsigned short* __restrict__ Bt,
    int mode,                                // 0 = QKV scatter, 1 = out + bias
    unsigned short* __restrict__ Qb,
    unsigned short* __restrict__ Kb,
    unsigned short* __restrict__ Vb,
    float* __restrict__ Out,
    const float* __restrict__ bias) {
    __shared__ unsigned short As[3 * AS_SLOT];   // 48 KB
    __shared__ unsigned short Bs[3 * BS_SLOT];   // 24 KB
    int t = threadIdx.x;

    // T1: XCD-aware remap (bijective: nwg = 768 or 256, both % 8 == 0)
    int gx   = (int)gridDim.x;
    int nwg  = gx * (int)gridDim.y;
    int flat = (int)(blockIdx.y * gridDim.x + blockIdx.x);
    int cpx  = nwg >> 3;
    int wid  = (flat & 7) * cpx + (flat >> 3);
    int m0 = (wid / gx) * 256;
    int n0 = (wid % gx) * 128;

    int wave = t >> 6, lane = t & 63;
    int quad = lane >> 4, lrow = lane & 15;
    int wr = (wave & 3) * 64;    // M offset of wave tile (4 waves)
    int wc = (wave >> 2) * 64;   // N offset of wave tile (2 waves)

    ffrag acc[4][4];
    const ffrag fz = {0.f, 0.f, 0.f, 0.f};
#pragma unroll
    for (int i = 0; i < 4; i++)
#pragma unroll
        for (int j = 0; j < 4; j++) acc[i][j] = fz;

    // staging (per tile): A = 1024 chunks of 8 (c0 = t rows 0-127, c1 = 512+t
    // rows 128-255), B = 512 chunks (c = t rows 0-127). XOR group swizzle
    // (proven): chunk c -> row r = c>>2, logical k-group g = (c&3)^((r>>1)&3).
    int r0 = t >> 2,        g0 = (t & 3) ^ ((r0 >> 1) & 3);
    int c1 = 512 + t;
    int r1 = c1 >> 2,       g1 = (c1 & 3) ^ ((r1 >> 1) & 3);
    const unsigned short* pA0 = A  + (size_t)(m0 + r0) * D_MODEL + g0 * 8;
    const unsigned short* pA1 = A  + (size_t)(m0 + r1) * D_MODEL + g1 * 8;
    const unsigned short* pB0 = Bt + (size_t)(n0 + r0) * D_MODEL + g0 * 8;
    unsigned short* lA0 = &As[(wave * 64) * 8];
    unsigned short* lA1 = &As[(512 + wave * 64) * 8];
    unsigned short* lB0 = &Bs[(wave * 64) * 8];

    // prologue: tile 0 -> slot 0, tile 1 -> slot 1 (3 g2l16/thread per tile)
    g2l16(pA0, lA0);
    g2l16(pA1, lA1);
    g2l16(pB0, lB0);
    g2l16(pA0 + 32, lA0 + AS_SLOT);
    g2l16(pA1 + 32, lA1 + AS_SLOT);
    g2l16(pB0 + 32, lB0 + BS_SLOT);

    int aCur = 0, aNxt = AS_SLOT, aSpr = 2 * AS_SLOT;
    int bCur = 0, bNxt = BS_SLOT, bSpr = 2 * BS_SLOT;

    for (int kt = 0; kt < NKT - 1; ++kt) {
        // drain tile kt's 3 loads; tile kt+1's ride across the barrier
        asm volatile("s_waitcnt vmcnt(3)\n\ts_barrier" ::: "memory");
        __builtin_amdgcn_sched_barrier(0);
        if (kt + 2 < NKT) {   // stage kt+2 into spare slot (= tile kt-1's)
            int ko = (kt + 2) * 32;
            g2l16(pA0 + ko, lA0 + aSpr);
            g2l16(pA1 + ko, lA1 + aSpr);
            g2l16(pB0 + ko, lB0 + bSpr);
        }
        bfrag af[4], bf[4];
#pragma unroll
        for (int ni = 0; ni < 4; ni++) {
            int row = wc + ni * 16 + lrow;
            bf[ni] = ld_frag(&Bs[bCur + row * 32 + ((quad ^ ((row >> 1) & 3)) * 8)]);
        }
#pragma unroll
        for (int mi = 0; mi < 4; mi++) {
            int row = wr + mi * 16 + lrow;
            af[mi] = ld_frag(&As[aCur + row * 32 + ((quad ^ ((row >> 1) & 3)) * 8)]);
        }
        __builtin_amdgcn_s_setprio(1);
#pragma unroll
        for (int mi = 0; mi < 4; mi++)
#pragma unroll
            for (int ni = 0; ni < 4; ni++)
                acc[mi][ni] = MFMA_BF16(af[mi], bf[ni], acc[mi][ni], 0, 0, 0);
        __builtin_amdgcn_s_setprio(0);
        int ta = aCur; aCur = aNxt; aNxt = aSpr; aSpr = ta;
        int tb = bCur; bCur = bNxt; bNxt = bSpr; bSpr = tb;
    }
    // peeled last tile: full drain
    asm volatile("s_waitcnt vmcnt(0)\n\ts_barrier" ::: "memory");
    __builtin_amdgcn_sched_barrier(0);
    {
        bfrag af[4], bf[4];
#pragma unroll
        for (int ni = 0; ni < 4; ni++) {
            int row = wc + ni * 16 + lrow;
            bf[ni] = ld_frag(&Bs[bCur + row * 32 + ((quad ^ ((row >> 1) & 3)) * 8)]);
        }
#pragma unroll
        for (int mi = 0; mi < 4; mi++) {
            int row = wr + mi * 16 + lrow;
            af[mi] = ld_frag(&As[aCur + row * 32 + ((quad ^ ((row >> 1) & 3)) * 8)]);
        }
#pragma unroll
        for (int mi = 0; mi < 4; mi++)
#pragma unroll
            for (int ni = 0; ni < 4; ni++)
                acc[mi][ni] = MFMA_BF16(af[mi], bf[ni], acc[mi][ni], 0, 0, 0);
    }

    // epilogue — row = m0+wr+mi*16+quad*4+r, col = n0+wc+ni*16+lrow.
    // FULLY UNROLLED (rule #20, R3/R16 lesson).
#pragma unroll
    for (int mi = 0; mi < 4; mi++) {
        int row = m0 + wr + mi * 16 + quad * 4;
#pragma unroll
        for (int ni = 0; ni < 4; ni++) {
            int col = n0 + wc + ni * 16 + lrow;
#pragma unroll
            for (int r = 0; r < 4; r++) {
                float v = acc[mi][ni][r];
                int m = row + r;
                if (mode == 0) {
                    int matid = col >> 10;
                    int nn = col & 1023;
                    int h = nn >> 6, d = nn & 63;
                    int b = m >> 11, s = m & 2047;
                    size_t bh = (size_t)(b * NH + h);
                    if (matid == 0)      Qb[(bh * S_LEN + s) * HDIM + d] = f2bf(v);
                    else if (matid == 1) Kb[(bh * S_LEN + s) * HDIM + d] = f2bf(v);
                    else                 Vb[(bh * S_LEN + s) * HDIM + d] = f2bf(v);
                } else {
                    Out[(size_t)m * D_MODEL + col] = v + bias[col];
                }
            }
        }
    }
}

// ---------------- flash attention v10 (unchanged from R2/R4/R5 pass) ----------------
#define SCALE2 0.18033688f  // 1/sqrt(64) * log2(e)
#define CSHIFT 4.0f
#define KVBUF 4096          // elems per K (or V) buffer: 64*64

__global__ __launch_bounds__(256, 4) void attn_kernel(
    const unsigned short* __restrict__ Qb,
    const unsigned short* __restrict__ Kb,
    const unsigned short* __restrict__ Vtb,
    unsigned short* __restrict__ ctxb) {
    __shared__ unsigned short Ks[2 * KVBUF];      // [buf][key][d]  swizzled
    __shared__ unsigned short Vs[2 * KVBUF];      // [buf][d][key]  swizzled
    __shared__ unsigned short Ps[4 * 16 * 64];    // per wave: [q(16)][key(64)] swizzled
    int flat = (int)(blockIdx.y * gridDim.x + blockIdx.x);   // 1024 blocks
    int wid  = (flat & 7) * 128 + (flat >> 3);
    int bx = wid & 15;    // 0..15
    int bh = wid >> 4;    // 0..63
    int t = threadIdx.x;
    int wave = t >> 6, lane = t & 63;
    int quad = lane >> 4, lrow = lane & 15;
    int swz = lrow & 7;
    int ca = (quad ^ swz) * 8;        // physical elem offset of logical chunk quad
    int cb = ca ^ 32;                 // logical chunk quad+4

    union { uint4 u; bfrag b; } one_u;
    one_u.u.x = 0x3F803F80u; one_u.u.y = 0x3F803F80u;
    one_u.u.z = 0x3F803F80u; one_u.u.w = 0x3F803F80u;
    bfrag onef = one_u.b;             // all-ones A-frag for l row-sum MFMA

    const unsigned short* Qg = Qb + (size_t)bh * S_LEN * HDIM;
    const unsigned short* Kg = Kb + (size_t)bh * S_LEN * HDIM;
    const unsigned short* Vg = Vtb + (size_t)bh * HDIM * S_LEN;
    int b = bh >> 4, h = bh & 15;

    int c0 = t, c1 = 256 + t;
    int kr0 = c0 >> 3, kp0 = (c0 & 7) ^ (kr0 & 7);
    int kr1 = c1 >> 3, kp1 = (c1 & 7) ^ (kr1 & 7);
    const unsigned short* pK0 = Kg + (size_t)kr0 * HDIM + kp0 * 8;
    const unsigned short* pK1 = Kg + (size_t)kr1 * HDIM + kp1 * 8;
    const unsigned short* pV0 = Vg + (size_t)kr0 * S_LEN + kp0 * 8;
    const unsigned short* pV1 = Vg + (size_t)kr1 * S_LEN + kp1 * 8;
    unsigned short* lK0 = &Ks[(wave * 64) * 8];
    unsigned short* lK1 = &Ks[(256 + wave * 64) * 8];
    unsigned short* lV0 = &Vs[(wave * 64) * 8];
    unsigned short* lV1 = &Vs[(256 + wave * 64) * 8];
    unsigned short* Pw = &Ps[wave * 16 * 64];

    for (int ph = 0; ph < 2; ph++) {
        int qc = ph == 0 ? (31 - bx) : bx;   // 64-row q chunk index
        int qw = qc * 64 + wave * 16;
        int nk = qc + 1;

        bfrag qf[2];
#pragma unroll
        for (int c = 0; c < 2; c++)
            qf[c] = ld_frag(Qg + (size_t)(qw + lrow) * HDIM + c * 32 + quad * 8);

        ffrag acc[4];
        ffrag acc_l;
        const ffrag fz = {0.f, 0.f, 0.f, 0.f};
#pragma unroll
        for (int d = 0; d < 4; d++) acc[d] = fz;
        acc_l = fz;

        __syncthreads();
        g2l16(pK0, lK0);
        g2l16(pK1, lK1);
        g2l16(pV0, lV0);
        g2l16(pV1, lV1);

        for (int kt = 0; kt < nk; kt++) {
            int kbase = kt * 64;
            int buf = (kt & 1) * KVBUF;
            __syncthreads();
            if (kt + 1 < nk) {
                int nb = ((kt + 1) & 1) * KVBUF;
                size_t krow_off = (size_t)(kbase + 64) * HDIM;
                g2l16(pK0 + krow_off, lK0 + nb);
                g2l16(pK1 + krow_off, lK1 + nb);
                g2l16(pV0 + kbase + 64, lV0 + nb);
                g2l16(pV1 + kbase + 64, lV1 + nb);
            }

            // ---- S^T = K Q^T ----
            ffrag sf[4];
#pragma unroll
            for (int ki = 0; ki < 4; ki++) {
                int krow = buf + (ki * 16 + lrow) * 64;
                bfrag ka = ld_frag(&Ks[krow + ca]);
                bfrag kb = ld_frag(&Ks[krow + cb]);
                ffrag s = fz;
                s = __builtin_amdgcn_mfma_f32_16x16x32_bf16(ka, qf[0], s, 0, 0, 0);
                s = __builtin_amdgcn_mfma_f32_16x16x32_bf16(kb, qf[1], s, 0, 0, 0);
                sf[ki] = s;
            }

            // ---- fixed-shift softmax (mask only on the diagonal tile) ----
            int qg = qw + lrow;                  // this lane's q
            bool need_mask = (kt == nk - 1);     // block-uniform
            float sv[16];
#pragma unroll
            for (int ki = 0; ki < 4; ki++)
#pragma unroll
                for (int r = 0; r < 4; r++) {
                    float v = sf[ki][r];
                    if (need_mask) {
                        int key = kbase + ki * 16 + quad * 4 + r;
                        v = (key <= qg) ? v : -3.0e38f;
                    }
                    sv[ki * 4 + r] = fast_exp2(__builtin_fmaf(v, SCALE2, -CSHIFT));
                }
            int prow = lrow * 64;
#pragma unroll
            for (int ki = 0; ki < 4; ki++) {
                uint2 w2;
                w2.x = pack_bf16(sv[ki * 4 + 0], sv[ki * 4 + 1]);
                w2.y = pack_bf16(sv[ki * 4 + 2], sv[ki * 4 + 3]);
                int pc = ((ki * 2 + (quad >> 1)) ^ swz) * 8 + (quad & 1) * 4;
                *(uint2*)&Pw[prow + pc] = w2;
            }

            // ---- O^T += V^T P^T ----  (Pw wave-private, DS in-order: no barrier)
            bfrag pf0 = ld_frag(&Pw[prow + ca]);
            bfrag pf1 = ld_frag(&Pw[prow + cb]);
            acc_l = __builtin_amdgcn_mfma_f32_16x16x32_bf16(onef, pf0, acc_l, 0, 0, 0);
            acc_l = __builtin_amdgcn_mfma_f32_16x16x32_bf16(onef, pf1, acc_l, 0, 0, 0);
#pragma unroll
            for (int di = 0; di < 4; di++) {
                int vrow = buf + (di * 16 + lrow) * 64;
                bfrag va = ld_frag(&Vs[vrow + ca]);
                bfrag vb = ld_frag(&Vs[vrow + cb]);
                acc[di] = __builtin_amdgcn_mfma_f32_16x16x32_bf16(va, pf0, acc[di], 0, 0, 0);
                acc[di] = __builtin_amdgcn_mfma_f32_16x16x32_bf16(vb, pf1, acc[di], 0, 0, 0);
            }
        }

        // epilogue: transpose O^T -> O via wave-private LDS, coalesced 16B stores.
        float rl = __builtin_amdgcn_rcpf(acc_l[0]);  // all rows equal; lane lrow=q
#pragma unroll
        for (int di = 0; di < 4; di++) {
            uint2 w2;
            w2.x = pack_bf16(acc[di][0] * rl, acc[di][1] * rl);
            w2.y = pack_bf16(acc[di][2] * rl, acc[di][3] * rl);
            *(uint2*)&Pw[lrow * 64 + di * 16 + quad * 4] = w2;
        }
        int ql = lane >> 3, cc = lane & 7;
#pragma unroll
        for (int p = 0; p < 2; p++) {
            uint4 vv = *(uint4*)&Pw[(p * 8 + ql) * 64 + cc * 8];
            int q = qw + p * 8 + ql;
            *(uint4*)(ctxb + ((size_t)b * S_LEN + q) * D_MODEL + h * HDIM + cc * 8) = vv;
        }
    }
}

extern "C" void kernel_launch(void* const* d_in, const int* in_sizes, int n_in,
                              void* d_out, int out_size, void* d_ws, size_t ws_size,
                              hipStream_t stream) {
    const float* x   = (const float*)d_in[0];
    const float* W_q = (const float*)d_in[1];
    const float* W_k = (const float*)d_in[2];
    const float* W_v = (const float*)d_in[3];
    const float* W_o = (const float*)d_in[4];
    const float* b_o = (const float*)d_in[5];
    float* out = (float*)d_out;

    // workspace carve (elems, ushort).  Vb (row-layout V) aliases ctxb:
    // Vb is dead after transpose_v, before attn writes ctxb.
    unsigned short* xb   = (unsigned short*)d_ws;                    // 8192*1024
    unsigned short* Wt   = xb + (size_t)8192 * 1024;                 // 4*1024*1024
    unsigned short* Qb   = Wt + (size_t)4 * 1024 * 1024;             // 64*2048*64
    unsigned short* Kb   = Qb + (size_t)64 * 2048 * 64;
    unsigned short* Vtb  = Kb + (size_t)64 * 2048 * 64;
    unsigned short* ctxb = Vtb + (size_t)64 * 2048 * 64;             // 8192*1024
    unsigned short* Vb   = ctxb;
    unsigned short* Wto  = Wt + (size_t)3 * 1024 * 1024;

    // fused cast + weight transpose (one launch)
    prep_kernel<<<8192, 256, 0, stream>>>(x, W_q, W_k, W_v, W_o, xb, Wt);
    // QKV: M=8192, N=3072; 256x128 tiles -> 32x24 = 768 blocks (2/CU packing)
    gemm_kernel<<<dim3(24, 32), 512, 0, stream>>>(xb, Wt, 0, Qb, Kb, Vb, nullptr, nullptr);
    // V transpose [s][d] -> [d][s]
    transpose_v_kernel<<<dim3(32, 64), 256, 0, stream>>>(Vb, Vtb);
    // attention (split-q: block bx does 64-row chunks 31-bx then bx; 33 tiles each)
    attn_kernel<<<dim3(16, 64), 256, 0, stream>>>(Qb, Kb, Vtb, ctxb);
    // out proj: M=8192, N=1024, + bias; 32x8 = 256 blocks = 1/CU
    gemm_kernel<<<dim3(8, 32), 512, 0, stream>>>(ctxb, Wto, 1, nullptr, nullptr, nullptr, out, b_o);
}

// Round 7
// 246.013 us; speedup vs baseline: 1.6765x; 1.0885x over previous
//
#include <hip/hip_runtime.h>
#include <cstdint>

#define S_LEN 2048
#define D_MODEL 1024
#define NH 16
#define HDIM 64
#define BATCH 4

typedef __attribute__((ext_vector_type(8))) __bf16 bfrag;   // 8 bf16 = 4 VGPR
typedef __attribute__((ext_vector_type(4))) float ffrag;    // 4 f32 acc

__device__ __forceinline__ unsigned short f2bf(float f) {
    union { float f; uint32_t u; } v; v.f = f;
    uint32_t u = v.u;
    u += 0x7fff + ((u >> 16) & 1);   // round-to-nearest-even
    return (unsigned short)(u >> 16);
}

__device__ __forceinline__ bfrag ld_frag(const unsigned short* p) {
    union { uint4 u; bfrag b; } x;
    x.u = *(const uint4*)p;
    return x.b;
}

__device__ __forceinline__ float fast_exp2(float x) {
#if __has_builtin(__builtin_amdgcn_exp2f)
    return __builtin_amdgcn_exp2f(x);
#else
    return __expf(x * 0.6931471805599453f);
#endif
}

// pack two f32 -> packed bf16x2 (round-half-up), 3 VALU inst
__device__ __forceinline__ uint32_t pack_bf16(float a, float b) {
    union { float f; uint32_t u; } x, y; x.f = a; y.f = b;
    return __builtin_amdgcn_perm(y.u + 0x8000u, x.u + 0x8000u, 0x07060302u);
}

__device__ __forceinline__ void g2l16(const unsigned short* g, unsigned short* l) {
    __builtin_amdgcn_global_load_lds(
        (const __attribute__((address_space(1))) void*)g,
        (__attribute__((address_space(3))) void*)l, 16, 0, 0);
}

// -------- fused prep: cast x (fp32->bf16) + cast/transpose weights ----------
__global__ __launch_bounds__(256) void prep_kernel(const float* __restrict__ x,
                                                   const float* __restrict__ w0,
                                                   const float* __restrict__ w1,
                                                   const float* __restrict__ w2,
                                                   const float* __restrict__ w3,
                                                   unsigned short* __restrict__ xb,
                                                   unsigned short* __restrict__ wt) {
    __shared__ float tile[32][33];
    int bid = blockIdx.x;
    int t = threadIdx.x;
    if (bid < 4096) {
        int i = bid * 256 + t;
        const float4* p = (const float4*)x + (size_t)i * 2;
        float4 a = p[0], b = p[1];
        union { unsigned short u[8]; uint4 v; } o;
        o.u[0]=f2bf(a.x); o.u[1]=f2bf(a.y); o.u[2]=f2bf(a.z); o.u[3]=f2bf(a.w);
        o.u[4]=f2bf(b.x); o.u[5]=f2bf(b.y); o.u[6]=f2bf(b.z); o.u[7]=f2bf(b.w);
        ((uint4*)xb)[i] = o.v;
    } else {
        int r = bid - 4096;
        int mat = r >> 10;
        int rem = r & 1023;
        const float* w = (mat == 0) ? w0 : (mat == 1) ? w1 : (mat == 2) ? w2 : w3;
        int n0 = (rem & 31) * 32, k0 = (rem >> 5) * 32;
        int tx = t & 31, ty = t >> 5;   // 32 x 8
        for (int i = 0; i < 32; i += 8)
            tile[ty + i][tx] = w[(size_t)(k0 + ty + i) * D_MODEL + n0 + tx];
        __syncthreads();
        unsigned short* o = wt + (size_t)mat * D_MODEL * D_MODEL;
        for (int i = 0; i < 32; i += 8)
            o[(size_t)(n0 + ty + i) * D_MODEL + (k0 + tx)] = f2bf(tile[tx][ty + i]);
    }
}

// ------------- V transpose: Vb[bh][s][d] -> Vtb[bh][d][s] (bf16) -------------
__global__ __launch_bounds__(256) void transpose_v_kernel(const unsigned short* __restrict__ Vb,
                                                          unsigned short* __restrict__ Vtb) {
    __shared__ unsigned short tile[64][72];
    int st = blockIdx.x;   // s-tile of 64
    int bh = blockIdx.y;
    int t = threadIdx.x;
    int sl = t >> 2, dc = (t & 3) * 16;
    const unsigned short* src = Vb + ((size_t)bh * S_LEN + st * 64 + sl) * HDIM + dc;
    *(uint4*)&tile[sl][dc]     = *(const uint4*)(src);
    *(uint4*)&tile[sl][dc + 8] = *(const uint4*)(src + 8);
    __syncthreads();
    int d = t >> 2, sc = (t & 3) * 16;
    union { unsigned short u[16]; uint4 v[2]; } o;
#pragma unroll
    for (int i = 0; i < 16; i++) o.u[i] = tile[sc + i][d];
    unsigned short* dst = Vtb + ((size_t)bh * HDIM + d) * S_LEN + st * 64 + sc;
    *(uint4*)(dst)     = o.v[0];
    *(uint4*)(dst + 8) = o.v[1];
}

#define MFMA_BF16 __builtin_amdgcn_mfma_f32_16x16x32_bf16

// ========== GEMM: C[M][N] = A[M][K=1024] * Bt[N][K]^T, 256 x (NF*32) tile ===
// R19: templated B-width. NF=4 (BN=128) is bit-identical to the R6 winner
// (69.4us QKV, MfmaUtil 30.5, Occ 31, 2 blk/CU). NF=2 (BN=64) fixes the
// out-proj packing: N=1024/64=16 -> grid 16x32 = 512 blocks = EXACTLY 2/CU
// on all 256 CUs (R6's 256-block launch spread 1/CU -> 2 waves/SIMD, the
// starved config R5 measured at ~22% MfmaUtil).
// B staging at NF=2: 256 chunks over 512 threads -> t and t+256 load the
// SAME chunk to the SAME LDS address (identical data -> benign; B panel is
// L2-resident so the dup global read is cheap). This keeps 3 loads/thread/
// tile UNIFORM across waves -> the proven vmcnt(3) ring is unchanged.
// Structure (twice-proven): ring-3 LDS, per tile "s_waitcnt vmcnt(3);
// s_barrier" fused + sched_barrier(0), stage kt+2, frags, setprio'd MFMA;
// tail peeled at vmcnt(0). launch_bounds(512,4) -> 4 waves/SIMD, 2 blk/CU.
// Spill tripwire (R3): if WRITE_SIZE >> expected, reg cap spilled.
#define AS_SLOT 8192    // 256 rows * 32 elems
#define NKT  (D_MODEL / 32)   // 32 k-tiles

template<int NF, int MODE>   // NF = B-frags per wave (BN = NF*32); MODE 0=QKV 1=out
__global__ __launch_bounds__(512, 4) void gemm_kernel(
    const unsigned short* __restrict__ A,
    const unsigned short* __restrict__ Bt,
    unsigned short* __restrict__ Qb,
    unsigned short* __restrict__ Kb,
    unsigned short* __restrict__ Vb,
    float* __restrict__ Out,
    const float* __restrict__ bias) {
    constexpr int BN = NF * 32;          // block N
    constexpr int BS_SLOT = BN * 32;     // B slot elems
    constexpr int NBCH = BN * 4;         // B chunks per tile
    constexpr int NWB = NBCH / 64;       // B-staging wave slices
    __shared__ unsigned short As[3 * AS_SLOT];
    __shared__ unsigned short Bs[3 * BS_SLOT];
    int t = threadIdx.x;

    // T1: XCD-aware remap (bijective: nwg = 768 or 512, both % 8 == 0)
    int gx   = (int)gridDim.x;
    int nwg  = gx * (int)gridDim.y;
    int flat = (int)(blockIdx.y * gridDim.x + blockIdx.x);
    int cpx  = nwg >> 3;
    int wid  = (flat & 7) * cpx + (flat >> 3);
    int m0 = (wid / gx) * 256;
    int n0 = (wid % gx) * BN;

    int wave = t >> 6, lane = t & 63;
    int quad = lane >> 4, lrow = lane & 15;
    int wr = (wave & 3) * 64;            // M offset of wave tile (4 waves)
    int wc = (wave >> 2) * (NF * 16);    // N offset of wave tile (2 waves)

    ffrag acc[4][NF];
    const ffrag fz = {0.f, 0.f, 0.f, 0.f};
#pragma unroll
    for (int i = 0; i < 4; i++)
#pragma unroll
        for (int j = 0; j < NF; j++) acc[i][j] = fz;

    // staging: A = 1024 chunks (c0 = t rows 0-127, c1 = 512+t rows 128-255);
    // B = NBCH chunks, thread covers chunk t & (NBCH-1) (dup x2 when NF=2).
    // XOR group swizzle (proven): chunk c -> row r=c>>2, g=(c&3)^((r>>1)&3).
    int r0 = t >> 2,        g0 = (t & 3) ^ ((r0 >> 1) & 3);
    int c1 = 512 + t;
    int r1 = c1 >> 2,       g1 = (c1 & 3) ^ ((r1 >> 1) & 3);
    int cbi = t & (NBCH - 1);
    int rB = cbi >> 2,      gB = (cbi & 3) ^ ((rB >> 1) & 3);
    const unsigned short* pA0 = A  + (size_t)(m0 + r0) * D_MODEL + g0 * 8;
    const unsigned short* pA1 = A  + (size_t)(m0 + r1) * D_MODEL + g1 * 8;
    const unsigned short* pB0 = Bt + (size_t)(n0 + rB) * D_MODEL + gB * 8;
    unsigned short* lA0 = &As[(wave * 64) * 8];
    unsigned short* lA1 = &As[(512 + wave * 64) * 8];
    unsigned short* lB0 = &Bs[((wave & (NWB - 1)) * 64) * 8];

    // prologue: tile 0 -> slot 0, tile 1 -> slot 1 (3 g2l16/thread per tile)
    g2l16(pA0, lA0);
    g2l16(pA1, lA1);
    g2l16(pB0, lB0);
    g2l16(pA0 + 32, lA0 + AS_SLOT);
    g2l16(pA1 + 32, lA1 + AS_SLOT);
    g2l16(pB0 + 32, lB0 + BS_SLOT);

    int aCur = 0, aNxt = AS_SLOT, aSpr = 2 * AS_SLOT;
    int bCur = 0, bNxt = BS_SLOT, bSpr = 2 * BS_SLOT;

    for (int kt = 0; kt < NKT - 1; ++kt) {
        // drain tile kt's 3 loads; tile kt+1's ride across the barrier
        asm volatile("s_waitcnt vmcnt(3)\n\ts_barrier" ::: "memory");
        __builtin_amdgcn_sched_barrier(0);
        if (kt + 2 < NKT) {   // stage kt+2 into spare slot (= tile kt-1's)
            int ko = (kt + 2) * 32;
            g2l16(pA0 + ko, lA0 + aSpr);
            g2l16(pA1 + ko, lA1 + aSpr);
            g2l16(pB0 + ko, lB0 + bSpr);
        }
        bfrag af[4], bf[NF];
#pragma unroll
        for (int ni = 0; ni < NF; ni++) {
            int row = wc + ni * 16 + lrow;
            bf[ni] = ld_frag(&Bs[bCur + row * 32 + ((quad ^ ((row >> 1) & 3)) * 8)]);
        }
#pragma unroll
        for (int mi = 0; mi < 4; mi++) {
            int row = wr + mi * 16 + lrow;
            af[mi] = ld_frag(&As[aCur + row * 32 + ((quad ^ ((row >> 1) & 3)) * 8)]);
        }
        __builtin_amdgcn_s_setprio(1);
#pragma unroll
        for (int mi = 0; mi < 4; mi++)
#pragma unroll
            for (int ni = 0; ni < NF; ni++)
                acc[mi][ni] = MFMA_BF16(af[mi], bf[ni], acc[mi][ni], 0, 0, 0);
        __builtin_amdgcn_s_setprio(0);
        int ta = aCur; aCur = aNxt; aNxt = aSpr; aSpr = ta;
        int tb = bCur; bCur = bNxt; bNxt = bSpr; bSpr = tb;
    }
    // peeled last tile: full drain
    asm volatile("s_waitcnt vmcnt(0)\n\ts_barrier" ::: "memory");
    __builtin_amdgcn_sched_barrier(0);
    {
        bfrag af[4], bf[NF];
#pragma unroll
        for (int ni = 0; ni < NF; ni++) {
            int row = wc + ni * 16 + lrow;
            bf[ni] = ld_frag(&Bs[bCur + row * 32 + ((quad ^ ((row >> 1) & 3)) * 8)]);
        }
#pragma unroll
        for (int mi = 0; mi < 4; mi++) {
            int row = wr + mi * 16 + lrow;
            af[mi] = ld_frag(&As[aCur + row * 32 + ((quad ^ ((row >> 1) & 3)) * 8)]);
        }
#pragma unroll
        for (int mi = 0; mi < 4; mi++)
#pragma unroll
            for (int ni = 0; ni < NF; ni++)
                acc[mi][ni] = MFMA_BF16(af[mi], bf[ni], acc[mi][ni], 0, 0, 0);
    }

    // epilogue — row = m0+wr+mi*16+quad*4+r, col = n0+wc+ni*16+lrow.
    // FULLY UNROLLED (rule #20, R3/R16 lesson).
#pragma unroll
    for (int mi = 0; mi < 4; mi++) {
        int row = m0 + wr + mi * 16 + quad * 4;
#pragma unroll
        for (int ni = 0; ni < NF; ni++) {
            int col = n0 + wc + ni * 16 + lrow;
#pragma unroll
            for (int r = 0; r < 4; r++) {
                float v = acc[mi][ni][r];
                int m = row + r;
                if (MODE == 0) {
                    int matid = col >> 10;
                    int nn = col & 1023;
                    int h = nn >> 6, d = nn & 63;
                    int b = m >> 11, s = m & 2047;
                    size_t bh = (size_t)(b * NH + h);
                    if (matid == 0)      Qb[(bh * S_LEN + s) * HDIM + d] = f2bf(v);
                    else if (matid == 1) Kb[(bh * S_LEN + s) * HDIM + d] = f2bf(v);
                    else                 Vb[(bh * S_LEN + s) * HDIM + d] = f2bf(v);
                } else {
                    Out[(size_t)m * D_MODEL + col] = v + bias[col];
                }
            }
        }
    }
}

// ---------------- flash attention v10 (unchanged from R2/R4/R5/R6 pass) ----------------
#define SCALE2 0.18033688f  // 1/sqrt(64) * log2(e)
#define CSHIFT 4.0f
#define KVBUF 4096          // elems per K (or V) buffer: 64*64

__global__ __launch_bounds__(256, 4) void attn_kernel(
    const unsigned short* __restrict__ Qb,
    const unsigned short* __restrict__ Kb,
    const unsigned short* __restrict__ Vtb,
    unsigned short* __restrict__ ctxb) {
    __shared__ unsigned short Ks[2 * KVBUF];      // [buf][key][d]  swizzled
    __shared__ unsigned short Vs[2 * KVBUF];      // [buf][d][key]  swizzled
    __shared__ unsigned short Ps[4 * 16 * 64];    // per wave: [q(16)][key(64)] swizzled
    int flat = (int)(blockIdx.y * gridDim.x + blockIdx.x);   // 1024 blocks
    int wid  = (flat & 7) * 128 + (flat >> 3);
    int bx = wid & 15;    // 0..15
    int bh = wid >> 4;    // 0..63
    int t = threadIdx.x;
    int wave = t >> 6, lane = t & 63;
    int quad = lane >> 4, lrow = lane & 15;
    int swz = lrow & 7;
    int ca = (quad ^ swz) * 8;        // physical elem offset of logical chunk quad
    int cb = ca ^ 32;                 // logical chunk quad+4

    union { uint4 u; bfrag b; } one_u;
    one_u.u.x = 0x3F803F80u; one_u.u.y = 0x3F803F80u;
    one_u.u.z = 0x3F803F80u; one_u.u.w = 0x3F803F80u;
    bfrag onef = one_u.b;             // all-ones A-frag for l row-sum MFMA

    const unsigned short* Qg = Qb + (size_t)bh * S_LEN * HDIM;
    const unsigned short* Kg = Kb + (size_t)bh * S_LEN * HDIM;
    const unsigned short* Vg = Vtb + (size_t)bh * HDIM * S_LEN;
    int b = bh >> 4, h = bh & 15;

    int c0 = t, c1 = 256 + t;
    int kr0 = c0 >> 3, kp0 = (c0 & 7) ^ (kr0 & 7);
    int kr1 = c1 >> 3, kp1 = (c1 & 7) ^ (kr1 & 7);
    const unsigned short* pK0 = Kg + (size_t)kr0 * HDIM + kp0 * 8;
    const unsigned short* pK1 = Kg + (size_t)kr1 * HDIM + kp1 * 8;
    const unsigned short* pV0 = Vg + (size_t)kr0 * S_LEN + kp0 * 8;
    const unsigned short* pV1 = Vg + (size_t)kr1 * S_LEN + kp1 * 8;
    unsigned short* lK0 = &Ks[(wave * 64) * 8];
    unsigned short* lK1 = &Ks[(256 + wave * 64) * 8];
    unsigned short* lV0 = &Vs[(wave * 64) * 8];
    unsigned short* lV1 = &Vs[(256 + wave * 64) * 8];
    unsigned short* Pw = &Ps[wave * 16 * 64];

    for (int ph = 0; ph < 2; ph++) {
        int qc = ph == 0 ? (31 - bx) : bx;   // 64-row q chunk index
        int qw = qc * 64 + wave * 16;
        int nk = qc + 1;

        bfrag qf[2];
#pragma unroll
        for (int c = 0; c < 2; c++)
            qf[c] = ld_frag(Qg + (size_t)(qw + lrow) * HDIM + c * 32 + quad * 8);

        ffrag acc[4];
        ffrag acc_l;
        const ffrag fz = {0.f, 0.f, 0.f, 0.f};
#pragma unroll
        for (int d = 0; d < 4; d++) acc[d] = fz;
        acc_l = fz;

        __syncthreads();
        g2l16(pK0, lK0);
        g2l16(pK1, lK1);
        g2l16(pV0, lV0);
        g2l16(pV1, lV1);

        for (int kt = 0; kt < nk; kt++) {
            int kbase = kt * 64;
            int buf = (kt & 1) * KVBUF;
            __syncthreads();
            if (kt + 1 < nk) {
                int nb = ((kt + 1) & 1) * KVBUF;
                size_t krow_off = (size_t)(kbase + 64) * HDIM;
                g2l16(pK0 + krow_off, lK0 + nb);
                g2l16(pK1 + krow_off, lK1 + nb);
                g2l16(pV0 + kbase + 64, lV0 + nb);
                g2l16(pV1 + kbase + 64, lV1 + nb);
            }

            // ---- S^T = K Q^T ----
            ffrag sf[4];
#pragma unroll
            for (int ki = 0; ki < 4; ki++) {
                int krow = buf + (ki * 16 + lrow) * 64;
                bfrag ka = ld_frag(&Ks[krow + ca]);
                bfrag kb = ld_frag(&Ks[krow + cb]);
                ffrag s = fz;
                s = __builtin_amdgcn_mfma_f32_16x16x32_bf16(ka, qf[0], s, 0, 0, 0);
                s = __builtin_amdgcn_mfma_f32_16x16x32_bf16(kb, qf[1], s, 0, 0, 0);
                sf[ki] = s;
            }

            // ---- fixed-shift softmax (mask only on the diagonal tile) ----
            int qg = qw + lrow;                  // this lane's q
            bool need_mask = (kt == nk - 1);     // block-uniform
            float sv[16];
#pragma unroll
            for (int ki = 0; ki < 4; ki++)
#pragma unroll
                for (int r = 0; r < 4; r++) {
                    float v = sf[ki][r];
                    if (need_mask) {
                        int key = kbase + ki * 16 + quad * 4 + r;
                        v = (key <= qg) ? v : -3.0e38f;
                    }
                    sv[ki * 4 + r] = fast_exp2(__builtin_fmaf(v, SCALE2, -CSHIFT));
                }
            int prow = lrow * 64;
#pragma unroll
            for (int ki = 0; ki < 4; ki++) {
                uint2 w2;
                w2.x = pack_bf16(sv[ki * 4 + 0], sv[ki * 4 + 1]);
                w2.y = pack_bf16(sv[ki * 4 + 2], sv[ki * 4 + 3]);
                int pc = ((ki * 2 + (quad >> 1)) ^ swz) * 8 + (quad & 1) * 4;
                *(uint2*)&Pw[prow + pc] = w2;
            }

            // ---- O^T += V^T P^T ----  (Pw wave-private, DS in-order: no barrier)
            bfrag pf0 = ld_frag(&Pw[prow + ca]);
            bfrag pf1 = ld_frag(&Pw[prow + cb]);
            acc_l = __builtin_amdgcn_mfma_f32_16x16x32_bf16(onef, pf0, acc_l, 0, 0, 0);
            acc_l = __builtin_amdgcn_mfma_f32_16x16x32_bf16(onef, pf1, acc_l, 0, 0, 0);
#pragma unroll
            for (int di = 0; di < 4; di++) {
                int vrow = buf + (di * 16 + lrow) * 64;
                bfrag va = ld_frag(&Vs[vrow + ca]);
                bfrag vb = ld_frag(&Vs[vrow + cb]);
                acc[di] = __builtin_amdgcn_mfma_f32_16x16x32_bf16(va, pf0, acc[di], 0, 0, 0);
                acc[di] = __builtin_amdgcn_mfma_f32_16x16x32_bf16(vb, pf1, acc[di], 0, 0, 0);
            }
        }

        // epilogue: transpose O^T -> O via wave-private LDS, coalesced 16B stores.
        float rl = __builtin_amdgcn_rcpf(acc_l[0]);  // all rows equal; lane lrow=q
#pragma unroll
        for (int di = 0; di < 4; di++) {
            uint2 w2;
            w2.x = pack_bf16(acc[di][0] * rl, acc[di][1] * rl);
            w2.y = pack_bf16(acc[di][2] * rl, acc[di][3] * rl);
            *(uint2*)&Pw[lrow * 64 + di * 16 + quad * 4] = w2;
        }
        int ql = lane >> 3, cc = lane & 7;
#pragma unroll
        for (int p = 0; p < 2; p++) {
            uint4 vv = *(uint4*)&Pw[(p * 8 + ql) * 64 + cc * 8];
            int q = qw + p * 8 + ql;
            *(uint4*)(ctxb + ((size_t)b * S_LEN + q) * D_MODEL + h * HDIM + cc * 8) = vv;
        }
    }
}

extern "C" void kernel_launch(void* const* d_in, const int* in_sizes, int n_in,
                              void* d_out, int out_size, void* d_ws, size_t ws_size,
                              hipStream_t stream) {
    const float* x   = (const float*)d_in[0];
    const float* W_q = (const float*)d_in[1];
    const float* W_k = (const float*)d_in[2];
    const float* W_v = (const float*)d_in[3];
    const float* W_o = (const float*)d_in[4];
    const float* b_o = (const float*)d_in[5];
    float* out = (float*)d_out;

    // workspace carve (elems, ushort).  Vb (row-layout V) aliases ctxb:
    // Vb is dead after transpose_v, before attn writes ctxb.
    unsigned short* xb   = (unsigned short*)d_ws;                    // 8192*1024
    unsigned short* Wt   = xb + (size_t)8192 * 1024;                 // 4*1024*1024
    unsigned short* Qb   = Wt + (size_t)4 * 1024 * 1024;             // 64*2048*64
    unsigned short* Kb   = Qb + (size_t)64 * 2048 * 64;
    unsigned short* Vtb  = Kb + (size_t)64 * 2048 * 64;
    unsigned short* ctxb = Vtb + (size_t)64 * 2048 * 64;             // 8192*1024
    unsigned short* Vb   = ctxb;
    unsigned short* Wto  = Wt + (size_t)3 * 1024 * 1024;

    // fused cast + weight transpose (one launch)
    prep_kernel<<<8192, 256, 0, stream>>>(x, W_q, W_k, W_v, W_o, xb, Wt);
    // QKV: M=8192, N=3072; 256x128 tiles (NF=4) -> 24x32 = 768 blocks (2/CU)
    gemm_kernel<4, 0><<<dim3(24, 32), 512, 0, stream>>>(xb, Wt, Qb, Kb, Vb, nullptr, nullptr);
    // V transpose [s][d] -> [d][s]
    transpose_v_kernel<<<dim3(32, 64), 256, 0, stream>>>(Vb, Vtb);
    // attention (split-q: block bx does 64-row chunks 31-bx then bx; 33 tiles each)
    attn_kernel<<<dim3(16, 64), 256, 0, stream>>>(Qb, Kb, Vtb, ctxb);
    // out proj: M=8192, N=1024, + bias; 256x64 tiles (NF=2) -> 16x32 = 512
    // blocks = EXACTLY 2/CU on all 256 CUs (fixes R6's 256-block starvation)
    gemm_kernel<2, 1><<<dim3(16, 32), 512, 0, stream>>>(ctxb, Wto, nullptr, nullptr, nullptr, out, b_o);
}